// Round 3
// baseline (268.357 us; speedup 1.0000x reference)
//
#include <hip/hip_runtime.h>
#include <hip/hip_bf16.h>

typedef unsigned short ushort_t;
using f32x4  = __attribute__((ext_vector_type(4))) float;
using bf16x8 = __attribute__((ext_vector_type(8))) short;

#define N_PIX 4096

static __device__ __forceinline__ unsigned short f2bf(float f) {
  unsigned int u = __builtin_bit_cast(unsigned int, f);
  u += 0x7FFFu + ((u >> 16) & 1u);   // round-to-nearest-even
  return (unsigned short)(u >> 16);
}

typedef union {
  uint4 u4;
  unsigned long long q[2];
  bf16x8 v;
} fragU;

#define LDS_U32(p) ((unsigned)(uintptr_t)((__attribute__((address_space(3))) void*)(p)))

// ---------------------------------------------------------------------------
// zero_span: zero a contiguous byte span (uint4 granularity)
// ---------------------------------------------------------------------------
__global__ __launch_bounds__(256) void zero_span_k(uint4* __restrict__ p, int n16) {
  int i = blockIdx.x * 256 + threadIdx.x;
  if (i < n16) p[i] = (uint4){0u, 0u, 0u, 0u};
}

// ---------------------------------------------------------------------------
// pack_w: build bf16 weight tensors
//   Wp_c [9][128][96]  from cam_enc_w [126][80][3][3]
//   Wp_f [9][128][512] from fuser_w  [126][504][3][3]
// ---------------------------------------------------------------------------
__global__ __launch_bounds__(256) void pack_w_k(
    const float* __restrict__ cam_enc_w, const float* __restrict__ fuser_w,
    ushort_t* __restrict__ Wp_c, ushort_t* __restrict__ Wp_f) {
  int idx = blockIdx.x * 256 + threadIdx.x;
  if (idx < 110592) {                     // 9*128*96
    int kk = idx / 12288, r = idx % 12288;
    int co = r / 96, ci = r % 96;
    float v = (co < 126 && ci < 80) ? cam_enc_w[(co * 80 + ci) * 9 + kk] : 0.f;
    Wp_c[idx] = f2bf(v);
  } else {
    int j = idx - 110592;
    if (j >= 589824) return;              // 9*128*512
    int kk = j / 65536, r = j % 65536;
    int co = r / 512, ci = r % 512;
    float v = (co < 126 && ci < 504) ? fuser_w[(co * 504 + ci) * 9 + kk] : 0.f;
    Wp_f[j] = f2bf(v);
  }
}

// ---------------------------------------------------------------------------
// convert_cam: cam_bev f32 [80][4096] -> camBF_main [96][66][64] (+y halo),
//                                        camBF_halo [96][66][66] (+y,x halo)
// ---------------------------------------------------------------------------
__global__ __launch_bounds__(256) void convert_cam_k(
    const float* __restrict__ cam, ushort_t* __restrict__ m,
    ushort_t* __restrict__ h) {
  int idx = blockIdx.x * 256 + threadIdx.x;   // 80*4096
  int ch = idx >> 12, n = idx & 4095;
  int y = n >> 6, x = n & 63;
  unsigned short b = f2bf(cam[idx]);
  m[ch * 4224 + (y + 1) * 64 + x] = b;
  h[ch * 4356 + (y + 1) * 66 + (x + 1)] = b;
}

// ---------------------------------------------------------------------------
// conv_mfma: implicit-GEMM 3x3 conv, one (ky,kx) tap per blockIdx.y.
// (unchanged from R2)
// ---------------------------------------------------------------------------
__global__ __launch_bounds__(256) void conv_mfma_k(
    const ushort_t* __restrict__ Amain,   // [CIp][66][64]
    const ushort_t* __restrict__ Ahalo,   // [CIp][66][66]
    const ushort_t* __restrict__ Wp,      // [9][128][CIp]
    float* __restrict__ parts,            // arena
    int CIp, int ksteps) {
  __shared__ __align__(16) ushort_t Abuf[2][2048];
  const int y   = blockIdx.x;
  const int kk  = blockIdx.y;
  const int ky  = kk / 3, kx = kk - ky * 3;
  const int tid = threadIdx.x;
  const int w   = tid >> 6, l = tid & 63;
  const int lane15 = l & 15, g = l >> 4;
  const int yy1 = y + ky;

  const int ci_l = w * 8 + (l >> 5) * 4 + ((l & 7) >> 1);
  const int m0   = ((l >> 3) & 3) * 16 + (l & 1) * 8;
  const ushort_t* src;
  size_t plane;
  if (kx == 1) { plane = 66 * 64; src = Amain + (size_t)ci_l * plane + yy1 * 64 + m0; }
  else         { plane = 66 * 66; src = Ahalo + (size_t)ci_l * plane + yy1 * 66 + m0 + kx; }

  const ushort_t* wbase = Wp + ((size_t)kk * 128 + w * 32 + lane15) * CIp + g * 8;
  const unsigned tr_base = LDS_U32(&Abuf[0][0]) + (unsigned)(g * 1024 + lane15 * 8);

  f32x4 acc[4][2];
  #pragma unroll
  for (int q = 0; q < 4; ++q) {
    acc[q][0] = (f32x4){0.f, 0.f, 0.f, 0.f};
    acc[q][1] = (f32x4){0.f, 0.f, 0.f, 0.f};
  }

  __builtin_amdgcn_global_load_lds(
      (const __attribute__((address_space(1))) unsigned*)src,
      (__attribute__((address_space(3))) unsigned*)(&Abuf[0][w * 512]), 16, 0, 0);
  __syncthreads();

  for (int s = 0; s < ksteps; ++s) {
    if (s + 1 < ksteps) {
      const ushort_t* srcn = src + (size_t)(s + 1) * 32 * plane;
      __builtin_amdgcn_global_load_lds(
          (const __attribute__((address_space(1))) unsigned*)srcn,
          (__attribute__((address_space(3))) unsigned*)(&Abuf[(s + 1) & 1][w * 512]), 16, 0, 0);
    }
    const ushort_t* wb = wbase + s * 32;
    fragU fb0, fb1;
    fb0.u4 = *(const uint4*)(wb);
    fb1.u4 = *(const uint4*)(wb + 16 * CIp);

    unsigned ta = tr_base + (unsigned)((s & 1) << 12);
    unsigned long long r00, r01, r10, r11, r20, r21, r30, r31;
    asm volatile("ds_read_b64_tr_b16 %0, %1 offset:0"   : "=v"(r00) : "v"(ta));
    asm volatile("ds_read_b64_tr_b16 %0, %1 offset:512" : "=v"(r01) : "v"(ta));
    asm volatile("ds_read_b64_tr_b16 %0, %1 offset:128" : "=v"(r10) : "v"(ta));
    asm volatile("ds_read_b64_tr_b16 %0, %1 offset:640" : "=v"(r11) : "v"(ta));
    asm volatile("ds_read_b64_tr_b16 %0, %1 offset:256" : "=v"(r20) : "v"(ta));
    asm volatile("ds_read_b64_tr_b16 %0, %1 offset:768" : "=v"(r21) : "v"(ta));
    asm volatile("ds_read_b64_tr_b16 %0, %1 offset:384" : "=v"(r30) : "v"(ta));
    asm volatile("ds_read_b64_tr_b16 %0, %1 offset:896" : "=v"(r31) : "v"(ta));
    asm volatile("s_waitcnt lgkmcnt(0)" ::: "memory");
    __builtin_amdgcn_sched_barrier(0);

    fragU fa;
    fa.q[0] = r00; fa.q[1] = r01;
    acc[0][0] = __builtin_amdgcn_mfma_f32_16x16x32_bf16(fa.v, fb0.v, acc[0][0], 0, 0, 0);
    acc[0][1] = __builtin_amdgcn_mfma_f32_16x16x32_bf16(fa.v, fb1.v, acc[0][1], 0, 0, 0);
    fa.q[0] = r10; fa.q[1] = r11;
    acc[1][0] = __builtin_amdgcn_mfma_f32_16x16x32_bf16(fa.v, fb0.v, acc[1][0], 0, 0, 0);
    acc[1][1] = __builtin_amdgcn_mfma_f32_16x16x32_bf16(fa.v, fb1.v, acc[1][1], 0, 0, 0);
    fa.q[0] = r20; fa.q[1] = r21;
    acc[2][0] = __builtin_amdgcn_mfma_f32_16x16x32_bf16(fa.v, fb0.v, acc[2][0], 0, 0, 0);
    acc[2][1] = __builtin_amdgcn_mfma_f32_16x16x32_bf16(fa.v, fb1.v, acc[2][1], 0, 0, 0);
    fa.q[0] = r30; fa.q[1] = r31;
    acc[3][0] = __builtin_amdgcn_mfma_f32_16x16x32_bf16(fa.v, fb0.v, acc[3][0], 0, 0, 0);
    acc[3][1] = __builtin_amdgcn_mfma_f32_16x16x32_bf16(fa.v, fb1.v, acc[3][1], 0, 0, 0);
    __syncthreads();
  }

  float* pout = parts + (size_t)kk * 524288 + (size_t)(w * 32 + lane15) * 4096
              + y * 64 + g * 4;
  #pragma unroll
  for (int q = 0; q < 4; ++q) {
    *(f32x4*)(pout + q * 16)               = acc[q][0];
    *(f32x4*)(pout + 16 * 4096 + q * 16)   = acc[q][1];
  }
}

// ---------------------------------------------------------------------------
// reduce9 (unchanged)
// ---------------------------------------------------------------------------
__global__ __launch_bounds__(256) void reduce9_k(
    const float* __restrict__ parts, float* __restrict__ out,
    const float* __restrict__ bias) {
  int n4 = blockIdx.x * 256 + threadIdx.x;
  int co = blockIdx.y;
  size_t off = (size_t)co * 4096 + n4 * 4;
  f32x4 s = (f32x4){0.f, 0.f, 0.f, 0.f};
  #pragma unroll
  for (int kk = 0; kk < 9; ++kk)
    s += *(const f32x4*)(parts + (size_t)kk * 524288 + off);
  if (bias) {
    float b = bias[co];
    s[0] += b; s[1] += b; s[2] += b; s[3] += b;
  }
  *(f32x4*)(out + off) = s;
}

// ---------------------------------------------------------------------------
// qkv projections -> bf16, vectorized 4 pixels/thread. Q pre-scaled by
// scale*log2e (flash attention runs softmax in exp2 domain).
// grid (4, 192), block 256.
// ---------------------------------------------------------------------------
__global__ __launch_bounds__(256) void qkv_k(
    const float* __restrict__ lidar_bev, const float* __restrict__ cam_enc,
    const float* __restrict__ lid_qk_w, const float* __restrict__ cam_qk_w,
    const float* __restrict__ cam_v_w, const float* __restrict__ lid_v_w,
    ushort_t* __restrict__ lidQK, ushort_t* __restrict__ camQK,
    ushort_t* __restrict__ camV, ushort_t* __restrict__ lidV) {
  int n0   = (blockIdx.x * 256 + threadIdx.x) * 4;
  int col0 = blockIdx.y * 4;
  const float* X; const float* W; int wr;
  if (col0 < 256)      { X = lidar_bev; W = lid_qk_w; wr = col0; }
  else if (col0 < 512) { X = cam_enc;   W = cam_qk_w; wr = col0 - 256; }
  else if (col0 < 640) { X = cam_enc;   W = cam_v_w;  wr = col0 - 512; }
  else                 { X = lidar_bev; W = lid_v_w;  wr = col0 - 640; }
  const float* w0 = W + wr * 126;
  f32x4 a0 = {0,0,0,0}, a1 = {0,0,0,0}, a2 = {0,0,0,0}, a3 = {0,0,0,0};
  for (int c = 0; c < 126; ++c) {
    f32x4 xv = *(const f32x4*)(X + (size_t)c * N_PIX + n0);
    a0 += xv * w0[c];
    a1 += xv * w0[126 + c];
    a2 += xv * w0[252 + c];
    a3 += xv * w0[378 + c];
  }
  if (col0 < 512) {
    const float QSCALE = 0.08908708063747479f * 1.4426950408889634f;
    float sc = (wr < 128) ? QSCALE : 1.f;    // rows 0..127 of qk_w are Q
    a0 *= sc; a1 *= sc; a2 *= sc; a3 *= sc;
    ushort_t* o = (col0 < 256) ? (lidQK + col0) : (camQK + (col0 - 256));
    #pragma unroll
    for (int i = 0; i < 4; ++i) {
      ushort4 pk; pk.x = f2bf(a0[i]); pk.y = f2bf(a1[i]);
      pk.z = f2bf(a2[i]); pk.w = f2bf(a3[i]);
      *(ushort4*)(o + (size_t)(n0 + i) * 256) = pk;
    }
  } else {
    ushort_t* o = (col0 < 640) ? (camV + (size_t)(col0 - 512) * N_PIX + n0)
                               : (lidV + (size_t)(col0 - 640) * N_PIX + n0);
    ushort4 p0, p1, p2, p3;
    p0.x=f2bf(a0[0]); p0.y=f2bf(a0[1]); p0.z=f2bf(a0[2]); p0.w=f2bf(a0[3]);
    p1.x=f2bf(a1[0]); p1.y=f2bf(a1[1]); p1.z=f2bf(a1[2]); p1.w=f2bf(a1[3]);
    p2.x=f2bf(a2[0]); p2.y=f2bf(a2[1]); p2.z=f2bf(a2[2]); p2.w=f2bf(a2[3]);
    p3.x=f2bf(a3[0]); p3.y=f2bf(a3[1]); p3.z=f2bf(a3[2]); p3.w=f2bf(a3[3]);
    *(ushort4*)(o)             = p0;
    *(ushort4*)(o + N_PIX)     = p1;
    *(ushort4*)(o + 2*N_PIX)   = p2;
    *(ushort4*)(o + 3*N_PIX)   = p3;
  }
}

// ---------------------------------------------------------------------------
// flash attention, swapped-QK lane-local softmax + async double-buffered K/V.
// grid (64, 4, 2), block 256 = 4 waves. QBLK=64 (16 q/wave), KBLK=64.
// Q pre-scaled by scale*log2e -> softmax in exp2 domain.
// Swapped S^T = mfma(K, Q): lane (m,g) holds S[q=w*16+m][k=nb*16+g*4+r].
// One __syncthreads per k-iter; next tile's global loads issued at iter top,
// LDS-written after PV (latency hidden under softmax+PV).
// ---------------------------------------------------------------------------
__global__ __launch_bounds__(256) void flash_attn_mfma(
    const ushort_t* __restrict__ lidQK, const ushort_t* __restrict__ camQK,
    const ushort_t* __restrict__ camV, const ushort_t* __restrict__ lidV,
    float* __restrict__ O1, float* __restrict__ O2,
    float* __restrict__ O3, float* __restrict__ O4) {
  const int i0   = blockIdx.x * 64;
  const int h    = blockIdx.y;
  const int attn = blockIdx.z;
  const ushort_t* QK = attn ? camQK : lidQK;
  float* Ocam = attn ? O3 : O1;
  float* Olid = attn ? O4 : O2;

  __shared__ __align__(16) ushort_t Ks[2][64 * 40];
  __shared__ __align__(16) ushort_t Vt[2][64 * 72];   // rows 0..31 cam, 32..63 lid
  __shared__ __align__(16) ushort_t Ps[64 * 72];      // also Q staging (64*40)

  const int tid = threadIdx.x;
  const int w = tid >> 6, l = tid & 63;
  const int m = l & 15, g = l >> 4;
  const int qrow = tid >> 2, qpart = tid & 3;   // Q/K staging coords
  const int vrow = tid >> 3, vpart = tid & 7;   // V staging coords

  // ---- prologue: Q through LDS; K0/V0 staged ----
  uint4 q4  = *(const uint4*)(QK + (size_t)(i0 + qrow) * 256 + h * 32 + qpart * 8);
  uint4 k4  = *(const uint4*)(QK + (size_t)qrow * 256 + 128 + h * 32 + qpart * 8);
  uint4 vc4 = *(const uint4*)(camV + (size_t)(h * 32 + vrow) * N_PIX + vpart * 8);
  uint4 vl4 = *(const uint4*)(lidV + (size_t)(h * 32 + vrow) * N_PIX + vpart * 8);
  *(uint4*)(&Ps[qrow * 40 + qpart * 8]) = q4;
  __syncthreads();
  bf16x8 qfrag = *(const bf16x8*)(&Ps[(w * 16 + m) * 40 + g * 8]);
  *(uint4*)(&Ks[0][qrow * 40 + qpart * 8]) = k4;
  *(uint4*)(&Vt[0][vrow * 72 + vpart * 8]) = vc4;
  *(uint4*)(&Vt[0][(vrow + 32) * 72 + vpart * 8]) = vl4;
  __syncthreads();

  f32x4 Oacc[4];
  #pragma unroll
  for (int t = 0; t < 4; ++t) Oacc[t] = (f32x4){0.f, 0.f, 0.f, 0.f};
  float mrun = -1e30f, lrun = 0.f;

  for (int j0 = 0; j0 < N_PIX; j0 += 64) {
    const int cur = (j0 >> 6) & 1, nxt = cur ^ 1;
    const bool more = (j0 + 64) < N_PIX;
    uint4 kn, vcn, vln;
    if (more) {   // issue next tile's loads (consumed after PV)
      kn  = *(const uint4*)(QK + (size_t)(j0 + 64 + qrow) * 256 + 128 + h * 32 + qpart * 8);
      vcn = *(const uint4*)(camV + (size_t)(h * 32 + vrow) * N_PIX + j0 + 64 + vpart * 8);
      vln = *(const uint4*)(lidV + (size_t)(h * 32 + vrow) * N_PIX + j0 + 64 + vpart * 8);
    }

    // S^T = K Q^T : lane (m,g) reg r -> S[q=w*16+m][k=nb*16+g*4+r]
    f32x4 S[4];
    #pragma unroll
    for (int nb = 0; nb < 4; ++nb) {
      bf16x8 kb = *(const bf16x8*)(&Ks[cur][(nb * 16 + m) * 40 + g * 8]);
      f32x4 z = (f32x4){0.f, 0.f, 0.f, 0.f};
      S[nb] = __builtin_amdgcn_mfma_f32_16x16x32_bf16(kb, qfrag, z, 0, 0, 0);
    }

    // lane-local softmax over 16 values, reduce across the 4 g-lanes
    float mx = fmaxf(fmaxf(fmaxf(S[0][0], S[0][1]), fmaxf(S[0][2], S[0][3])),
                     fmaxf(fmaxf(S[1][0], S[1][1]), fmaxf(S[1][2], S[1][3])));
    mx = fmaxf(mx, fmaxf(fmaxf(fmaxf(S[2][0], S[2][1]), fmaxf(S[2][2], S[2][3])),
                         fmaxf(fmaxf(S[3][0], S[3][1]), fmaxf(S[3][2], S[3][3]))));
    mx = fmaxf(mx, __shfl_xor(mx, 16));
    mx = fmaxf(mx, __shfl_xor(mx, 32));
    float mn = fmaxf(mrun, mx);
    float corr = exp2f(mrun - mn);
    float ps = 0.f;
    #pragma unroll
    for (int nb = 0; nb < 4; ++nb)
      #pragma unroll
      for (int r = 0; r < 4; ++r) {
        float p = exp2f(S[nb][r] - mn);
        S[nb][r] = p;
        ps += p;
      }
    ps += __shfl_xor(ps, 16);
    ps += __shfl_xor(ps, 32);
    lrun = lrun * corr + ps;
    mrun = mn;

    // broadcast corr to this lane's O rows (q = w*16 + g*4 + r)
    float cr[4];
    #pragma unroll
    for (int r = 0; r < 4; ++r) cr[r] = __shfl(corr, g * 4 + r);
    #pragma unroll
    for (int t = 0; t < 4; ++t)
      #pragma unroll
      for (int r = 0; r < 4; ++r) Oacc[t][r] *= cr[r];

    // P -> Ps bf16 (wave-private rows; 4 x 8B stores)
    #pragma unroll
    for (int nb = 0; nb < 4; ++nb) {
      ushort4 pk;
      pk.x = f2bf(S[nb][0]); pk.y = f2bf(S[nb][1]);
      pk.z = f2bf(S[nb][2]); pk.w = f2bf(S[nb][3]);
      *(ushort4*)(&Ps[(w * 16 + m) * 72 + nb * 16 + g * 4]) = pk;
    }

    // PV
    #pragma unroll
    for (int ks = 0; ks < 2; ++ks) {
      bf16x8 pa = *(const bf16x8*)(&Ps[(w * 16 + m) * 72 + ks * 32 + g * 8]);
      #pragma unroll
      for (int t = 0; t < 4; ++t) {
        bf16x8 vb = *(const bf16x8*)(&Vt[cur][(t * 16 + m) * 72 + ks * 32 + g * 8]);
        Oacc[t] = __builtin_amdgcn_mfma_f32_16x16x32_bf16(pa, vb, Oacc[t], 0, 0, 0);
      }
    }

    // write next tile into the other LDS buffer; one barrier per iter
    if (more) {
      *(uint4*)(&Ks[nxt][qrow * 40 + qpart * 8]) = kn;
      *(uint4*)(&Vt[nxt][vrow * 72 + vpart * 8]) = vcn;
      *(uint4*)(&Vt[nxt][(vrow + 32) * 72 + vpart * 8]) = vln;
    }
    __syncthreads();
  }

  // epilogue: lane (m,g) holds O[q=w*16+g*4+r][d=t*16+m]
  float lr[4];
  #pragma unroll
  for (int r = 0; r < 4; ++r) lr[r] = 1.0f / __shfl(lrun, g * 4 + r);
  #pragma unroll
  for (int t = 0; t < 4; ++t) {
    float* Obuf = (t < 2) ? Ocam : Olid;
    int d = h * 32 + (t & 1) * 16 + m;
    f32x4 o = Oacc[t];
    o[0] *= lr[0]; o[1] *= lr[1]; o[2] *= lr[2]; o[3] *= lr[3];
    *(f32x4*)(Obuf + (size_t)d * N_PIX + i0 + w * 16 + g * 4) = o;
  }
}

// ---------------------------------------------------------------------------
// proj_fuse: projections + residuals -> padded bf16 buffers, 4 pixels/thread.
// grid (4, 63), block 256.
// ---------------------------------------------------------------------------
__global__ __launch_bounds__(256) void proj_fuse_k(
    const float* __restrict__ O1, const float* __restrict__ O2,
    const float* __restrict__ O3, const float* __restrict__ O4,
    const float* __restrict__ cam_proj_w, const float* __restrict__ cam_proj_b,
    const float* __restrict__ lid_proj_w, const float* __restrict__ lid_proj_b,
    const float* __restrict__ cam_enc, const float* __restrict__ lidar_bev,
    ushort_t* __restrict__ fm, ushort_t* __restrict__ fh) {
  int n0 = (blockIdx.x * 256 + threadIdx.x) * 4;
  int c0 = blockIdx.y * 2;
  f32x4 a00={0,0,0,0},a01={0,0,0,0},a02={0,0,0,0},a03={0,0,0,0};
  f32x4 a10={0,0,0,0},a11={0,0,0,0},a12={0,0,0,0},a13={0,0,0,0};
  for (int k = 0; k < 128; ++k) {
    f32x4 o1 = *(const f32x4*)(O1 + (size_t)k * N_PIX + n0);
    f32x4 o2 = *(const f32x4*)(O2 + (size_t)k * N_PIX + n0);
    f32x4 o3 = *(const f32x4*)(O3 + (size_t)k * N_PIX + n0);
    f32x4 o4 = *(const f32x4*)(O4 + (size_t)k * N_PIX + n0);
    float wl0 = lid_proj_w[c0 * 128 + k],       wc0 = cam_proj_w[c0 * 128 + k];
    float wl1 = lid_proj_w[(c0 + 1) * 128 + k], wc1 = cam_proj_w[(c0 + 1) * 128 + k];
    a00 += o3 * wl0; a01 += o1 * wc0; a02 += o4 * wl0; a03 += o2 * wl0;
    a10 += o3 * wl1; a11 += o1 * wc1; a12 += o4 * wl1; a13 += o2 * wl1;
  }
  int y = n0 >> 6, x = n0 & 63;
  int mo = (y + 1) * 64 + x;
  int ho = (y + 1) * 66 + x + 1;
  #pragma unroll
  for (int cc = 0; cc < 2; ++cc) {
    int c = c0 + cc;
    const f32x4& b0 = cc ? a10 : a00; const f32x4& b1 = cc ? a11 : a01;
    const f32x4& b2 = cc ? a12 : a02; const f32x4& b3 = cc ? a13 : a03;
    f32x4 ce = *(const f32x4*)(cam_enc + (size_t)c * N_PIX + n0);
    f32x4 lb = *(const f32x4*)(lidar_bev + (size_t)c * N_PIX + n0);
    float bl = lid_proj_b[c], bc = cam_proj_b[c];
    ushort4 v0, v1, v2, v3;
    #pragma unroll
    for (int i = 0; i < 4; ++i) {
      ((ushort_t*)&v0)[i] = f2bf(ce[i] + b0[i] + bl);
      ((ushort_t*)&v1)[i] = f2bf(ce[i] + b1[i] + bc);
      ((ushort_t*)&v2)[i] = f2bf(lb[i] + b2[i] + bl);
      ((ushort_t*)&v3)[i] = f2bf(lb[i] + b3[i] + bl);
    }
    *(ushort4*)(&fm[(0   + c) * 4224 + mo]) = v0;
    *(ushort4*)(&fm[(126 + c) * 4224 + mo]) = v1;
    *(ushort4*)(&fm[(252 + c) * 4224 + mo]) = v2;
    *(ushort4*)(&fm[(378 + c) * 4224 + mo]) = v3;
    #pragma unroll
    for (int i = 0; i < 4; ++i) {
      fh[(0   + c) * 4356 + ho + i] = ((ushort_t*)&v0)[i];
      fh[(126 + c) * 4356 + ho + i] = ((ushort_t*)&v1)[i];
      fh[(252 + c) * 4356 + ho + i] = ((ushort_t*)&v2)[i];
      fh[(378 + c) * 4356 + ho + i] = ((ushort_t*)&v3)[i];
    }
  }
}

// ---------------------------------------------------------------------------
extern "C" void kernel_launch(void* const* d_in, const int* in_sizes, int n_in,
                              void* d_out, int out_size, void* d_ws, size_t ws_size,
                              hipStream_t stream) {
  (void)in_sizes; (void)n_in; (void)out_size; (void)ws_size;
  const float* lidar_bev  = (const float*)d_in[0];
  const float* cam_bev    = (const float*)d_in[1];
  const float* cam_enc_w  = (const float*)d_in[2];
  const float* cam_enc_b  = (const float*)d_in[3];
  const float* cam_v_w    = (const float*)d_in[4];
  const float* cam_qk_w   = (const float*)d_in[5];
  const float* cam_proj_w = (const float*)d_in[6];
  const float* cam_proj_b = (const float*)d_in[7];
  const float* lid_v_w    = (const float*)d_in[8];
  const float* lid_qk_w   = (const float*)d_in[9];
  const float* lid_proj_w = (const float*)d_in[10];
  const float* lid_proj_b = (const float*)d_in[11];
  const float* fuser_w    = (const float*)d_in[12];
  float* out = (float*)d_out;

  char* p = (char*)d_ws;
  float* arena = (float*)p;
  float* O1 = (float*)(p + 0);
  float* O2 = (float*)(p + 2097152);
  float* O3 = (float*)(p + 4194304);
  float* O4 = (float*)(p + 6291456);
  ushort_t* lidQK = (ushort_t*)(p + 8388608);
  ushort_t* camQK = (ushort_t*)(p + 10485760);
  ushort_t* camV  = (ushort_t*)(p + 12582912);
  ushort_t* lidV  = (ushort_t*)(p + 13631488);
  float*    cam_enc  = (float*)(p + 18874368);    // 126x4096 f32
  ushort_t* Wp_c     = (ushort_t*)(p + 20938752); // [9][128][96]
  ushort_t* Wp_f     = (ushort_t*)(p + 21159936); // [9][128][512]
  ushort_t* camBF_m  = (ushort_t*)(p + 22339584); // [96][66][64]
  ushort_t* camBF_h  = (ushort_t*)(p + 23150592); // [96][66][66]
  ushort_t* fusBF_m  = (ushort_t*)(p + 23986944); // [512][66][64]
  ushort_t* fusBF_h  = (ushort_t*)(p + 28312320); // [512][66][66]

  zero_span_k<<<2548, 256, 0, stream>>>((uint4*)(p + 22339584), 652080);
  pack_w_k<<<2736, 256, 0, stream>>>(cam_enc_w, fuser_w, Wp_c, Wp_f);
  convert_cam_k<<<1280, 256, 0, stream>>>(cam_bev, camBF_m, camBF_h);

  conv_mfma_k<<<dim3(64, 9), 256, 0, stream>>>(camBF_m, camBF_h, Wp_c, arena, 96, 3);
  reduce9_k<<<dim3(4, 126), 256, 0, stream>>>(arena, cam_enc, cam_enc_b);

  qkv_k<<<dim3(4, 192), 256, 0, stream>>>(lidar_bev, cam_enc, lid_qk_w, cam_qk_w,
                                          cam_v_w, lid_v_w, lidQK, camQK, camV, lidV);
  flash_attn_mfma<<<dim3(64, 4, 2), 256, 0, stream>>>(lidQK, camQK, camV, lidV, O1, O2, O3, O4);
  proj_fuse_k<<<dim3(4, 63), 256, 0, stream>>>(O1, O2, O3, O4, cam_proj_w, cam_proj_b,
                                               lid_proj_w, lid_proj_b, cam_enc, lidar_bev,
                                               fusBF_m, fusBF_h);

  conv_mfma_k<<<dim3(64, 9), 256, 0, stream>>>(fusBF_m, fusBF_h, Wp_f, arena, 512, 16);
  reduce9_k<<<dim3(4, 126), 256, 0, stream>>>(arena, out, nullptr);
}

// Round 4
// 147.478 us; speedup vs baseline: 1.8196x; 1.8196x over previous
//
#include <hip/hip_runtime.h>
#include <hip/hip_bf16.h>

typedef unsigned short ushort_t;
using f32x4  = __attribute__((ext_vector_type(4))) float;
using bf16x8 = __attribute__((ext_vector_type(8))) short;

#define N_PIX 4096

static __device__ __forceinline__ unsigned short f2bf(float f) {
  unsigned int u = __builtin_bit_cast(unsigned int, f);
  u += 0x7FFFu + ((u >> 16) & 1u);   // round-to-nearest-even
  return (unsigned short)(u >> 16);
}
static __device__ __forceinline__ float bf2f(unsigned int us) {
  return __builtin_bit_cast(float, us << 16);
}

typedef union {
  uint4 u4;
  unsigned long long q[2];
  bf16x8 v;
  unsigned short us[8];
} fragU;

#define LDS_U32(p) ((unsigned)(uintptr_t)((__attribute__((address_space(3))) void*)(p)))

// ---------------------------------------------------------------------------
__global__ __launch_bounds__(256) void zero_span_k(uint4* __restrict__ p, int n16) {
  int i = blockIdx.x * 256 + threadIdx.x;
  if (i < n16) p[i] = (uint4){0u, 0u, 0u, 0u};
}

// ---------------------------------------------------------------------------
// pack_w: bf16 weights: Wp_c [9][128][96], Wp_f [9][128][512],
//         Wp_lid/Wp_cam [128][128] (proj weights, co-padded)
// ---------------------------------------------------------------------------
__global__ __launch_bounds__(256) void pack_w_k(
    const float* __restrict__ cam_enc_w, const float* __restrict__ fuser_w,
    const float* __restrict__ lid_proj_w, const float* __restrict__ cam_proj_w,
    ushort_t* __restrict__ Wp_c, ushort_t* __restrict__ Wp_f,
    ushort_t* __restrict__ Wp_lid, ushort_t* __restrict__ Wp_cam) {
  int idx = blockIdx.x * 256 + threadIdx.x;
  if (idx < 110592) {                     // 9*128*96
    int kk = idx / 12288, r = idx % 12288;
    int co = r / 96, ci = r % 96;
    float v = (co < 126 && ci < 80) ? cam_enc_w[(co * 80 + ci) * 9 + kk] : 0.f;
    Wp_c[idx] = f2bf(v);
  } else if (idx < 700416) {              // 9*128*512
    int j = idx - 110592;
    int kk = j / 65536, r = j % 65536;
    int co = r / 512, ci = r % 512;
    float v = (co < 126 && ci < 504) ? fuser_w[(co * 504 + ci) * 9 + kk] : 0.f;
    Wp_f[j] = f2bf(v);
  } else if (idx < 716800) {              // 128*128
    int j = idx - 700416;
    int co = j >> 7, k = j & 127;
    Wp_lid[j] = f2bf(co < 126 ? lid_proj_w[co * 128 + k] : 0.f);
  } else if (idx < 733184) {
    int j = idx - 716800;
    int co = j >> 7, k = j & 127;
    Wp_cam[j] = f2bf(co < 126 ? cam_proj_w[co * 128 + k] : 0.f);
  }
}

// ---------------------------------------------------------------------------
__global__ __launch_bounds__(256) void convert_cam_k(
    const float* __restrict__ cam, ushort_t* __restrict__ m,
    ushort_t* __restrict__ h) {
  int idx = blockIdx.x * 256 + threadIdx.x;   // 80*4096
  int ch = idx >> 12, n = idx & 4095;
  int y = n >> 6, x = n & 63;
  unsigned short b = f2bf(cam[idx]);
  m[ch * 4224 + (y + 1) * 64 + x] = b;
  h[ch * 4356 + (y + 1) * 66 + (x + 1)] = b;
}

// ---------------------------------------------------------------------------
// conv_mfma: implicit-GEMM 3x3 conv, one (ky,kx) tap per blockIdx.y.
// Partials now bf16: parts regions [kk][128 co][4096 n] ushort.
// ---------------------------------------------------------------------------
__global__ __launch_bounds__(256) void conv_mfma_k(
    const ushort_t* __restrict__ Amain,   // [CIp][66][64]
    const ushort_t* __restrict__ Ahalo,   // [CIp][66][66]
    const ushort_t* __restrict__ Wp,      // [9][128][CIp]
    ushort_t* __restrict__ parts,
    int CIp, int ksteps) {
  __shared__ __align__(16) ushort_t Abuf[2][2048];
  const int y   = blockIdx.x;
  const int kk  = blockIdx.y;
  const int ky  = kk / 3, kx = kk - ky * 3;
  const int tid = threadIdx.x;
  const int w   = tid >> 6, l = tid & 63;
  const int lane15 = l & 15, g = l >> 4;
  const int yy1 = y + ky;

  const int ci_l = w * 8 + (l >> 5) * 4 + ((l & 7) >> 1);
  const int m0   = ((l >> 3) & 3) * 16 + (l & 1) * 8;
  const ushort_t* src;
  size_t plane;
  if (kx == 1) { plane = 66 * 64; src = Amain + (size_t)ci_l * plane + yy1 * 64 + m0; }
  else         { plane = 66 * 66; src = Ahalo + (size_t)ci_l * plane + yy1 * 66 + m0 + kx; }

  const ushort_t* wbase = Wp + ((size_t)kk * 128 + w * 32 + lane15) * CIp + g * 8;
  const unsigned tr_base = LDS_U32(&Abuf[0][0]) + (unsigned)(g * 1024 + lane15 * 8);

  f32x4 acc[4][2];
  #pragma unroll
  for (int q = 0; q < 4; ++q) {
    acc[q][0] = (f32x4){0.f, 0.f, 0.f, 0.f};
    acc[q][1] = (f32x4){0.f, 0.f, 0.f, 0.f};
  }

  __builtin_amdgcn_global_load_lds(
      (const __attribute__((address_space(1))) unsigned*)src,
      (__attribute__((address_space(3))) unsigned*)(&Abuf[0][w * 512]), 16, 0, 0);
  __syncthreads();

  for (int s = 0; s < ksteps; ++s) {
    if (s + 1 < ksteps) {
      const ushort_t* srcn = src + (size_t)(s + 1) * 32 * plane;
      __builtin_amdgcn_global_load_lds(
          (const __attribute__((address_space(1))) unsigned*)srcn,
          (__attribute__((address_space(3))) unsigned*)(&Abuf[(s + 1) & 1][w * 512]), 16, 0, 0);
    }
    const ushort_t* wb = wbase + s * 32;
    fragU fb0, fb1;
    fb0.u4 = *(const uint4*)(wb);
    fb1.u4 = *(const uint4*)(wb + 16 * CIp);

    unsigned ta = tr_base + (unsigned)((s & 1) << 12);
    unsigned long long r00, r01, r10, r11, r20, r21, r30, r31;
    asm volatile("ds_read_b64_tr_b16 %0, %1 offset:0"   : "=v"(r00) : "v"(ta));
    asm volatile("ds_read_b64_tr_b16 %0, %1 offset:512" : "=v"(r01) : "v"(ta));
    asm volatile("ds_read_b64_tr_b16 %0, %1 offset:128" : "=v"(r10) : "v"(ta));
    asm volatile("ds_read_b64_tr_b16 %0, %1 offset:640" : "=v"(r11) : "v"(ta));
    asm volatile("ds_read_b64_tr_b16 %0, %1 offset:256" : "=v"(r20) : "v"(ta));
    asm volatile("ds_read_b64_tr_b16 %0, %1 offset:768" : "=v"(r21) : "v"(ta));
    asm volatile("ds_read_b64_tr_b16 %0, %1 offset:384" : "=v"(r30) : "v"(ta));
    asm volatile("ds_read_b64_tr_b16 %0, %1 offset:896" : "=v"(r31) : "v"(ta));
    asm volatile("s_waitcnt lgkmcnt(0)" ::: "memory");
    __builtin_amdgcn_sched_barrier(0);

    fragU fa;
    fa.q[0] = r00; fa.q[1] = r01;
    acc[0][0] = __builtin_amdgcn_mfma_f32_16x16x32_bf16(fa.v, fb0.v, acc[0][0], 0, 0, 0);
    acc[0][1] = __builtin_amdgcn_mfma_f32_16x16x32_bf16(fa.v, fb1.v, acc[0][1], 0, 0, 0);
    fa.q[0] = r10; fa.q[1] = r11;
    acc[1][0] = __builtin_amdgcn_mfma_f32_16x16x32_bf16(fa.v, fb0.v, acc[1][0], 0, 0, 0);
    acc[1][1] = __builtin_amdgcn_mfma_f32_16x16x32_bf16(fa.v, fb1.v, acc[1][1], 0, 0, 0);
    fa.q[0] = r20; fa.q[1] = r21;
    acc[2][0] = __builtin_amdgcn_mfma_f32_16x16x32_bf16(fa.v, fb0.v, acc[2][0], 0, 0, 0);
    acc[2][1] = __builtin_amdgcn_mfma_f32_16x16x32_bf16(fa.v, fb1.v, acc[2][1], 0, 0, 0);
    fa.q[0] = r30; fa.q[1] = r31;
    acc[3][0] = __builtin_amdgcn_mfma_f32_16x16x32_bf16(fa.v, fb0.v, acc[3][0], 0, 0, 0);
    acc[3][1] = __builtin_amdgcn_mfma_f32_16x16x32_bf16(fa.v, fb1.v, acc[3][1], 0, 0, 0);
    __syncthreads();
  }

  ushort_t* pout = parts + (size_t)kk * 524288 + (size_t)(w * 32 + lane15) * 4096
                 + y * 64 + g * 4;
  #pragma unroll
  for (int q = 0; q < 4; ++q) {
    ushort4 p0, p1;
    p0.x = f2bf(acc[q][0][0]); p0.y = f2bf(acc[q][0][1]);
    p0.z = f2bf(acc[q][0][2]); p0.w = f2bf(acc[q][0][3]);
    p1.x = f2bf(acc[q][1][0]); p1.y = f2bf(acc[q][1][1]);
    p1.z = f2bf(acc[q][1][2]); p1.w = f2bf(acc[q][1][3]);
    *(ushort4*)(pout + q * 16)             = p0;
    *(ushort4*)(pout + 16 * 4096 + q * 16) = p1;
  }
}

// ---------------------------------------------------------------------------
// reduce9: out[co][n] = sum_kk bf16 parts[kk][co][n] (+ bias). grid (2,126).
// ---------------------------------------------------------------------------
__global__ __launch_bounds__(256) void reduce9_k(
    const ushort_t* __restrict__ parts, float* __restrict__ out,
    const float* __restrict__ bias) {
  int n0 = (blockIdx.x * 256 + threadIdx.x) * 8;
  int co = blockIdx.y;
  size_t off = (size_t)co * 4096 + n0;
  float s[8] = {0, 0, 0, 0, 0, 0, 0, 0};
  #pragma unroll
  for (int kk = 0; kk < 9; ++kk) {
    uint4 v = *(const uint4*)(parts + (size_t)kk * 524288 + off);
    s[0] += bf2f(v.x & 0xffffu); s[1] += bf2f(v.x >> 16);
    s[2] += bf2f(v.y & 0xffffu); s[3] += bf2f(v.y >> 16);
    s[4] += bf2f(v.z & 0xffffu); s[5] += bf2f(v.z >> 16);
    s[6] += bf2f(v.w & 0xffffu); s[7] += bf2f(v.w >> 16);
  }
  float b = bias ? bias[co] : 0.f;
  f32x4 o0 = {s[0] + b, s[1] + b, s[2] + b, s[3] + b};
  f32x4 o1 = {s[4] + b, s[5] + b, s[6] + b, s[7] + b};
  *(f32x4*)(out + off)     = o0;
  *(f32x4*)(out + off + 4) = o1;
}

// ---------------------------------------------------------------------------
// qkv projections -> bf16 (Q pre-scaled by scale*log2e). grid (4,192).
// ---------------------------------------------------------------------------
__global__ __launch_bounds__(256) void qkv_k(
    const float* __restrict__ lidar_bev, const float* __restrict__ cam_enc,
    const float* __restrict__ lid_qk_w, const float* __restrict__ cam_qk_w,
    const float* __restrict__ cam_v_w, const float* __restrict__ lid_v_w,
    ushort_t* __restrict__ lidQK, ushort_t* __restrict__ camQK,
    ushort_t* __restrict__ camV, ushort_t* __restrict__ lidV) {
  int n0   = (blockIdx.x * 256 + threadIdx.x) * 4;
  int col0 = blockIdx.y * 4;
  const float* X; const float* W; int wr;
  if (col0 < 256)      { X = lidar_bev; W = lid_qk_w; wr = col0; }
  else if (col0 < 512) { X = cam_enc;   W = cam_qk_w; wr = col0 - 256; }
  else if (col0 < 640) { X = cam_enc;   W = cam_v_w;  wr = col0 - 512; }
  else                 { X = lidar_bev; W = lid_v_w;  wr = col0 - 640; }
  const float* w0 = W + wr * 126;
  f32x4 a0 = {0,0,0,0}, a1 = {0,0,0,0}, a2 = {0,0,0,0}, a3 = {0,0,0,0};
  for (int c = 0; c < 126; ++c) {
    f32x4 xv = *(const f32x4*)(X + (size_t)c * N_PIX + n0);
    a0 += xv * w0[c];
    a1 += xv * w0[126 + c];
    a2 += xv * w0[252 + c];
    a3 += xv * w0[378 + c];
  }
  if (col0 < 512) {
    const float QSCALE = 0.08908708063747479f * 1.4426950408889634f;
    float sc = (wr < 128) ? QSCALE : 1.f;
    a0 *= sc; a1 *= sc; a2 *= sc; a3 *= sc;
    ushort_t* o = (col0 < 256) ? (lidQK + col0) : (camQK + (col0 - 256));
    #pragma unroll
    for (int i = 0; i < 4; ++i) {
      ushort4 pk; pk.x = f2bf(a0[i]); pk.y = f2bf(a1[i]);
      pk.z = f2bf(a2[i]); pk.w = f2bf(a3[i]);
      *(ushort4*)(o + (size_t)(n0 + i) * 256) = pk;
    }
  } else {
    ushort_t* o = (col0 < 640) ? (camV + (size_t)(col0 - 512) * N_PIX + n0)
                               : (lidV + (size_t)(col0 - 640) * N_PIX + n0);
    ushort4 p0, p1, p2, p3;
    p0.x=f2bf(a0[0]); p0.y=f2bf(a0[1]); p0.z=f2bf(a0[2]); p0.w=f2bf(a0[3]);
    p1.x=f2bf(a1[0]); p1.y=f2bf(a1[1]); p1.z=f2bf(a1[2]); p1.w=f2bf(a1[3]);
    p2.x=f2bf(a2[0]); p2.y=f2bf(a2[1]); p2.z=f2bf(a2[2]); p2.w=f2bf(a2[3]);
    p3.x=f2bf(a3[0]); p3.y=f2bf(a3[1]); p3.z=f2bf(a3[2]); p3.w=f2bf(a3[3]);
    *(ushort4*)(o)           = p0;
    *(ushort4*)(o + N_PIX)   = p1;
    *(ushort4*)(o + 2*N_PIX) = p2;
    *(ushort4*)(o + 3*N_PIX) = p3;
  }
}

// ---------------------------------------------------------------------------
// flash attention v3: key-split x2, defer-rescale, cvt_pk P-pack.
// grid (64 qblk, 4 h, 4 = attn*2+half), block 256 = 4 waves.
// Each block: 2048 keys; stores UNNORMALIZED bf16 O-partials [a][h][v][n][d]
// + per-row (m,l) in ML. Softmax in exp2 domain (Q pre-scaled).
// ---------------------------------------------------------------------------
__global__ __launch_bounds__(256) void flash_attn_mfma(
    const ushort_t* __restrict__ lidQK, const ushort_t* __restrict__ camQK,
    const ushort_t* __restrict__ camV, const ushort_t* __restrict__ lidV,
    ushort_t* __restrict__ OP, float2* __restrict__ ML) {
  const int i0    = blockIdx.x * 64;
  const int h     = blockIdx.y;
  const int attn  = blockIdx.z >> 1;
  const int half  = blockIdx.z & 1;
  const int kbase = half * 2048;
  const ushort_t* QK = attn ? camQK : lidQK;

  __shared__ __align__(16) ushort_t Ks[2][64 * 40];
  __shared__ __align__(16) ushort_t Vt[2][64 * 72];
  __shared__ __align__(16) ushort_t Ps[64 * 72];

  const int tid = threadIdx.x;
  const int w = tid >> 6, l = tid & 63;
  const int m = l & 15, g = l >> 4;
  const int qrow = tid >> 2, qpart = tid & 3;
  const int vrow = tid >> 3, vpart = tid & 7;

  const ushort_t* Kp = QK + (size_t)(kbase + qrow) * 256 + 128 + h * 32 + qpart * 8;
  const ushort_t* Vc = camV + (size_t)(h * 32 + vrow) * N_PIX + kbase + vpart * 8;
  const ushort_t* Vl = lidV + (size_t)(h * 32 + vrow) * N_PIX + kbase + vpart * 8;

  uint4 q4  = *(const uint4*)(QK + (size_t)(i0 + qrow) * 256 + h * 32 + qpart * 8);
  uint4 k4  = *(const uint4*)Kp;
  uint4 vc4 = *(const uint4*)Vc;
  uint4 vl4 = *(const uint4*)Vl;
  *(uint4*)(&Ps[qrow * 40 + qpart * 8]) = q4;
  __syncthreads();
  bf16x8 qfrag = *(const bf16x8*)(&Ps[(w * 16 + m) * 40 + g * 8]);
  *(uint4*)(&Ks[0][qrow * 40 + qpart * 8]) = k4;
  *(uint4*)(&Vt[0][vrow * 72 + vpart * 8]) = vc4;
  *(uint4*)(&Vt[0][(vrow + 32) * 72 + vpart * 8]) = vl4;
  __syncthreads();

  f32x4 Oacc[4];
  #pragma unroll
  for (int t = 0; t < 4; ++t) Oacc[t] = (f32x4){0.f, 0.f, 0.f, 0.f};
  float mrun = -1e30f, lrun = 0.f;

  for (int it = 0; it < 32; ++it) {
    const int cur = it & 1, nxt = cur ^ 1;
    const bool more = (it + 1) < 32;
    uint4 kn, vcn, vln;
    if (more) {
      kn  = *(const uint4*)(Kp + (size_t)(it + 1) * 16384);
      vcn = *(const uint4*)(Vc + (it + 1) * 64);
      vln = *(const uint4*)(Vl + (it + 1) * 64);
    }

    // S^T = K Q^T : lane (m,g) reg r -> S[q=w*16+m][k=nb*16+g*4+r]
    f32x4 S[4];
    #pragma unroll
    for (int nb = 0; nb < 4; ++nb) {
      bf16x8 kb = *(const bf16x8*)(&Ks[cur][(nb * 16 + m) * 40 + g * 8]);
      f32x4 z = (f32x4){0.f, 0.f, 0.f, 0.f};
      S[nb] = __builtin_amdgcn_mfma_f32_16x16x32_bf16(kb, qfrag, z, 0, 0, 0);
    }

    float mx = fmaxf(fmaxf(fmaxf(S[0][0], S[0][1]), fmaxf(S[0][2], S[0][3])),
                     fmaxf(fmaxf(S[1][0], S[1][1]), fmaxf(S[1][2], S[1][3])));
    mx = fmaxf(mx, fmaxf(fmaxf(fmaxf(S[2][0], S[2][1]), fmaxf(S[2][2], S[2][3])),
                         fmaxf(fmaxf(S[3][0], S[3][1]), fmaxf(S[3][2], S[3][3]))));
    mx = fmaxf(mx, __shfl_xor(mx, 16));
    mx = fmaxf(mx, __shfl_xor(mx, 32));

    if (__any(mx > mrun + 8.f)) {        // rare rescale path (defer-max, thr=8)
      float mn = fmaxf(mrun, mx);
      float corr = __builtin_amdgcn_exp2f(mrun - mn);
      #pragma unroll
      for (int r = 0; r < 4; ++r) {
        float cr = __shfl(corr, g * 4 + r);
        #pragma unroll
        for (int t = 0; t < 4; ++t) Oacc[t][r] *= cr;
      }
      lrun *= corr;
      mrun = mn;
    }

    float ps = 0.f;
    #pragma unroll
    for (int nb = 0; nb < 4; ++nb)
      #pragma unroll
      for (int r = 0; r < 4; ++r) {
        float p = __builtin_amdgcn_exp2f(S[nb][r] - mrun);
        S[nb][r] = p;
        ps += p;
      }
    ps += __shfl_xor(ps, 16);
    ps += __shfl_xor(ps, 32);
    lrun += ps;

    // P -> Ps bf16 via packed converts (wave-private rows)
    #pragma unroll
    for (int nb = 0; nb < 4; ++nb) {
      unsigned d0, d1;
      asm("v_cvt_pk_bf16_f32 %0, %1, %2" : "=v"(d0) : "v"(S[nb][0]), "v"(S[nb][1]));
      asm("v_cvt_pk_bf16_f32 %0, %1, %2" : "=v"(d1) : "v"(S[nb][2]), "v"(S[nb][3]));
      uint2 dd; dd.x = d0; dd.y = d1;
      *(uint2*)(&Ps[(w * 16 + m) * 72 + nb * 16 + g * 4]) = dd;
    }

    #pragma unroll
    for (int ks = 0; ks < 2; ++ks) {
      bf16x8 pa = *(const bf16x8*)(&Ps[(w * 16 + m) * 72 + ks * 32 + g * 8]);
      #pragma unroll
      for (int t = 0; t < 4; ++t) {
        bf16x8 vb = *(const bf16x8*)(&Vt[cur][(t * 16 + m) * 72 + ks * 32 + g * 8]);
        Oacc[t] = __builtin_amdgcn_mfma_f32_16x16x32_bf16(pa, vb, Oacc[t], 0, 0, 0);
      }
    }

    if (more) {
      *(uint4*)(&Ks[nxt][qrow * 40 + qpart * 8]) = kn;
      *(uint4*)(&Vt[nxt][vrow * 72 + vpart * 8]) = vcn;
      *(uint4*)(&Vt[nxt][(vrow + 32) * 72 + vpart * 8]) = vln;
    }
    __syncthreads();
  }

  // epilogue: unnormalized bf16 partials [a][h][v][n][d]; ML per q-row
  ushort_t* OPc = OP + (size_t)((attn * 2 + half) * 2 + 0) * 4096 * 128;
  ushort_t* OPl = OP + (size_t)((attn * 2 + half) * 2 + 1) * 4096 * 128;
  #pragma unroll
  for (int t = 0; t < 4; ++t) {
    ushort_t* Ob = (t < 2) ? OPc : OPl;
    int d = h * 32 + (t & 1) * 16 + m;
    #pragma unroll
    for (int r = 0; r < 4; ++r) {
      int n = i0 + w * 16 + g * 4 + r;
      Ob[(size_t)n * 128 + d] = f2bf(Oacc[t][r]);
    }
  }
  if (g == 0) {
    float2 v; v.x = mrun; v.y = lrun;
    ML[(size_t)(attn * 2 + half) * 4096 + i0 + w * 16 + m] = v;
  }
}

// ---------------------------------------------------------------------------
// proj_mfma: inline key-split combine + projection GEMM + residual + bias
// -> padded bf16 fuser-conv inputs. grid (64 nblk, 4 ot), block 256.
//   ot 0: cam_bev_c  = cam_enc + lidW(OP[a1][cam]);  ch base 0
//   ot 1: cam_bev_l  = cam_enc + camW(OP[a0][cam]);  ch base 126
//   ot 2: lidar_bev_c= lidar   + lidW(OP[a1][lid]);  ch base 252
//   ot 3: lidar_bev_l= lidar   + lidW(OP[a0][lid]);  ch base 378
// ---------------------------------------------------------------------------
__global__ __launch_bounds__(256) void proj_mfma_k(
    const ushort_t* __restrict__ OP, const float2* __restrict__ ML,
    const ushort_t* __restrict__ Wlid, const ushort_t* __restrict__ Wcam,
    const float* __restrict__ cam_enc, const float* __restrict__ lidar_bev,
    const float* __restrict__ cam_proj_b, const float* __restrict__ lid_proj_b,
    ushort_t* __restrict__ fm, ushort_t* __restrict__ fh) {
  const int n0 = blockIdx.x * 64;
  const int ot = blockIdx.y;
  const int attn = (ot == 0 || ot == 2) ? 1 : 0;
  const int vt = ot >> 1;
  const int tid = threadIdx.x;
  const int w = tid >> 6, l = tid & 63;
  const int m = l & 15, g = l >> 4;

  const ushort_t* Oa = OP + (size_t)((attn * 2 + 0) * 2 + vt) * 4096 * 128;
  const ushort_t* Ob = OP + (size_t)((attn * 2 + 1) * 2 + vt) * 4096 * 128;
  const float2* MLa = ML + (size_t)(attn * 2 + 0) * 4096;
  const float2* MLb = ML + (size_t)(attn * 2 + 1) * 4096;

  const int arow = n0 + w * 16 + m;
  float2 mla = MLa[arow], mlb = MLb[arow];
  float M  = fmaxf(mla.x, mlb.x);
  float wa = __builtin_amdgcn_exp2f(mla.x - M);
  float wb = __builtin_amdgcn_exp2f(mlb.x - M);
  float dn = wa * mla.y + wb * mlb.y;
  float aa = wa / dn, ab = wb / dn;

  fragU afr[4];
  #pragma unroll
  for (int s = 0; s < 4; ++s) {
    fragU xa, xb;
    xa.u4 = *(const uint4*)(Oa + (size_t)arow * 128 + s * 32 + g * 8);
    xb.u4 = *(const uint4*)(Ob + (size_t)arow * 128 + s * 32 + g * 8);
    #pragma unroll
    for (int j = 0; j < 8; ++j)
      afr[s].us[j] = f2bf(aa * bf2f(xa.us[j]) + ab * bf2f(xb.us[j]));
  }

  const ushort_t* W = (ot == 1) ? Wcam : Wlid;
  f32x4 acc[8];
  #pragma unroll
  for (int t = 0; t < 8; ++t) acc[t] = (f32x4){0.f, 0.f, 0.f, 0.f};
  #pragma unroll
  for (int s = 0; s < 4; ++s) {
    #pragma unroll
    for (int t = 0; t < 8; ++t) {
      fragU bfr;
      bfr.u4 = *(const uint4*)(W + (size_t)(t * 16 + m) * 128 + s * 32 + g * 8);
      acc[t] = __builtin_amdgcn_mfma_f32_16x16x32_bf16(afr[s].v, bfr.v, acc[t], 0, 0, 0);
    }
  }

  const float* res  = (ot < 2) ? cam_enc : lidar_bev;
  const float* bias = (ot == 1) ? cam_proj_b : lid_proj_b;
  const int doff = ot * 126;
  #pragma unroll
  for (int t = 0; t < 8; ++t) {
    int co = t * 16 + m;
    if (co < 126) {
      float b = bias[co];
      #pragma unroll
      for (int r = 0; r < 4; ++r) {
        int n = n0 + w * 16 + g * 4 + r;
        float v = acc[t][r] + res[(size_t)co * N_PIX + n] + b;
        unsigned short bf = f2bf(v);
        int y = n >> 6, x = n & 63;
        fm[(doff + co) * 4224 + (y + 1) * 64 + x]      = bf;
        fh[(doff + co) * 4356 + (y + 1) * 66 + x + 1]  = bf;
      }
    }
  }
}

// ---------------------------------------------------------------------------
extern "C" void kernel_launch(void* const* d_in, const int* in_sizes, int n_in,
                              void* d_out, int out_size, void* d_ws, size_t ws_size,
                              hipStream_t stream) {
  (void)in_sizes; (void)n_in; (void)out_size; (void)ws_size;
  const float* lidar_bev  = (const float*)d_in[0];
  const float* cam_bev    = (const float*)d_in[1];
  const float* cam_enc_w  = (const float*)d_in[2];
  const float* cam_enc_b  = (const float*)d_in[3];
  const float* cam_v_w    = (const float*)d_in[4];
  const float* cam_qk_w   = (const float*)d_in[5];
  const float* cam_proj_w = (const float*)d_in[6];
  const float* cam_proj_b = (const float*)d_in[7];
  const float* lid_v_w    = (const float*)d_in[8];
  const float* lid_qk_w   = (const float*)d_in[9];
  const float* lid_proj_w = (const float*)d_in[10];
  const float* lid_proj_b = (const float*)d_in[11];
  const float* fuser_w    = (const float*)d_in[12];
  float* out = (float*)d_out;

  char* p = (char*)d_ws;
  // arena [0, 9437184): 9 x [128][4096] bf16 conv partials (conv phases)
  // OP/ML alias arena (attention phase, disjoint in time):
  ushort_t* arena = (ushort_t*)p;
  ushort_t* OP    = (ushort_t*)p;                  // [2a][2h][2v][4096][128] bf16 = 8 MB
  float2*   ML    = (float2*)(p + 8388608);        // [2a][2h][4096] float2 = 128 KB
  ushort_t* lidQK = (ushort_t*)(p + 9437184);      // [4096][256] bf16
  ushort_t* camQK = (ushort_t*)(p + 11534336);
  ushort_t* camV  = (ushort_t*)(p + 13631488);     // [128][4096] bf16
  ushort_t* lidV  = (ushort_t*)(p + 14680064);
  float*    cam_enc = (float*)(p + 15728640);      // [126][4096] f32
  ushort_t* Wp_c    = (ushort_t*)(p + 17793024);   // [9][128][96]
  ushort_t* Wp_f    = (ushort_t*)(p + 18014208);   // [9][128][512]
  ushort_t* Wp_lid  = (ushort_t*)(p + 19193856);   // [128][128]
  ushort_t* Wp_cam  = (ushort_t*)(p + 19226624);   // [128][128]
  ushort_t* camBF_m = (ushort_t*)(p + 19259392);   // [96][66][64]
  ushort_t* camBF_h = (ushort_t*)(p + 20070400);   // [96][66][66]
  ushort_t* fusBF_m = (ushort_t*)(p + 20906752);   // [512][66][64]
  ushort_t* fusBF_h = (ushort_t*)(p + 25232128);   // [512][66][66] (end 29692672)

  zero_span_k<<<2548, 256, 0, stream>>>((uint4*)(p + 19259392), 652080);
  pack_w_k<<<2864, 256, 0, stream>>>(cam_enc_w, fuser_w, lid_proj_w, cam_proj_w,
                                     Wp_c, Wp_f, Wp_lid, Wp_cam);
  convert_cam_k<<<1280, 256, 0, stream>>>(cam_bev, camBF_m, camBF_h);

  conv_mfma_k<<<dim3(64, 9), 256, 0, stream>>>(camBF_m, camBF_h, Wp_c, arena, 96, 3);
  reduce9_k<<<dim3(2, 126), 256, 0, stream>>>(arena, cam_enc, cam_enc_b);

  qkv_k<<<dim3(4, 192), 256, 0, stream>>>(lidar_bev, cam_enc, lid_qk_w, cam_qk_w,
                                          cam_v_w, lid_v_w, lidQK, camQK, camV, lidV);
  flash_attn_mfma<<<dim3(64, 4, 4), 256, 0, stream>>>(lidQK, camQK, camV, lidV, OP, ML);
  proj_mfma_k<<<dim3(64, 4), 256, 0, stream>>>(OP, ML, Wp_lid, Wp_cam, cam_enc, lidar_bev,
                                               cam_proj_b, lid_proj_b, fusBF_m, fusBF_h);

  conv_mfma_k<<<dim3(64, 9), 256, 0, stream>>>(fusBF_m, fusBF_h, Wp_f, arena, 512, 16);
  reduce9_k<<<dim3(2, 126), 256, 0, stream>>>(arena, out, nullptr);
}

// Round 5
// 128.208 us; speedup vs baseline: 2.0931x; 1.1503x over previous
//
#include <hip/hip_runtime.h>
#include <hip/hip_bf16.h>

typedef unsigned short ushort_t;
using f32x4  = __attribute__((ext_vector_type(4))) float;
using bf16x8 = __attribute__((ext_vector_type(8))) short;

#define N_PIX 4096

static __device__ __forceinline__ unsigned short f2bf(float f) {
  unsigned int u = __builtin_bit_cast(unsigned int, f);
  u += 0x7FFFu + ((u >> 16) & 1u);   // round-to-nearest-even
  return (unsigned short)(u >> 16);
}
static __device__ __forceinline__ float bf2f(unsigned int us) {
  return __builtin_bit_cast(float, us << 16);
}

typedef union {
  uint4 u4;
  unsigned long long q[2];
  bf16x8 v;
  unsigned short us[8];
} fragU;

#define LDS_U32(p) ((unsigned)(uintptr_t)((__attribute__((address_space(3))) void*)(p)))

// ---------------------------------------------------------------------------
__global__ __launch_bounds__(256) void zero_span_k(uint4* __restrict__ p, int n16) {
  int i = blockIdx.x * 256 + threadIdx.x;
  if (i < n16) p[i] = (uint4){0u, 0u, 0u, 0u};
}

// ---------------------------------------------------------------------------
// pack_w: bf16 weights: Wp_c [9][128][96], Wp_f [9][128][512],
//   Wp_lid/Wp_cam [128][128] proj, Wq [6][128][128] qkv (Q rows pre-scaled).
// ---------------------------------------------------------------------------
__global__ __launch_bounds__(256) void pack_w_k(
    const float* __restrict__ cam_enc_w, const float* __restrict__ fuser_w,
    const float* __restrict__ lid_proj_w, const float* __restrict__ cam_proj_w,
    const float* __restrict__ lid_qk_w, const float* __restrict__ cam_qk_w,
    const float* __restrict__ cam_v_w, const float* __restrict__ lid_v_w,
    ushort_t* __restrict__ Wp_c, ushort_t* __restrict__ Wp_f,
    ushort_t* __restrict__ Wp_lid, ushort_t* __restrict__ Wp_cam,
    ushort_t* __restrict__ Wq) {
  const float QSCALE = 0.08908708063747479f * 1.4426950408889634f;
  int idx = blockIdx.x * 256 + threadIdx.x;
  if (idx < 110592) {                     // 9*128*96
    int kk = idx / 12288, r = idx % 12288;
    int co = r / 96, ci = r % 96;
    float v = (co < 126 && ci < 80) ? cam_enc_w[(co * 80 + ci) * 9 + kk] : 0.f;
    Wp_c[idx] = f2bf(v);
  } else if (idx < 700416) {              // 9*128*512
    int j = idx - 110592;
    int kk = j / 65536, r = j % 65536;
    int co = r / 512, ci = r % 512;
    float v = (co < 126 && ci < 504) ? fuser_w[(co * 504 + ci) * 9 + kk] : 0.f;
    Wp_f[j] = f2bf(v);
  } else if (idx < 716800) {              // 128*128
    int j = idx - 700416;
    int co = j >> 7, k = j & 127;
    Wp_lid[j] = f2bf(co < 126 ? lid_proj_w[co * 128 + k] : 0.f);
  } else if (idx < 733184) {
    int j = idx - 716800;
    int co = j >> 7, k = j & 127;
    Wp_cam[j] = f2bf(co < 126 ? cam_proj_w[co * 128 + k] : 0.f);
  } else if (idx < 831488) {              // 6*128*128
    int j = idx - 733184;
    int t = j >> 14, r = j & 16383;
    int row = r >> 7, ci = r & 127;
    float v = 0.f;
    if (ci < 126) {
      if (t == 0)      v = lid_qk_w[row * 126 + ci] * QSCALE;
      else if (t == 1) v = lid_qk_w[(128 + row) * 126 + ci];
      else if (t == 2) v = cam_qk_w[row * 126 + ci] * QSCALE;
      else if (t == 3) v = cam_qk_w[(128 + row) * 126 + ci];
      else if (t == 4) v = cam_v_w[row * 126 + ci];
      else             v = lid_v_w[row * 126 + ci];
    }
    Wq[j] = f2bf(v);
  }
}

// ---------------------------------------------------------------------------
// convert_in: cam_bev -> halo bf16 buffers; lidar_bev -> lidBF [126][4096]
// ---------------------------------------------------------------------------
__global__ __launch_bounds__(256) void convert_in_k(
    const float* __restrict__ cam, const float* __restrict__ lidar,
    ushort_t* __restrict__ m, ushort_t* __restrict__ h,
    ushort_t* __restrict__ lidBF) {
  int idx = blockIdx.x * 256 + threadIdx.x;
  if (idx < 327680) {                         // 80*4096
    int ch = idx >> 12, n = idx & 4095;
    int y = n >> 6, x = n & 63;
    unsigned short b = f2bf(cam[idx]);
    m[ch * 4224 + (y + 1) * 64 + x] = b;
    h[ch * 4356 + (y + 1) * 66 + (x + 1)] = b;
  } else {
    int j = idx - 327680;                     // 126*4096
    if (j < 516096) lidBF[j] = f2bf(lidar[j]);
  }
}

// ---------------------------------------------------------------------------
// conv_mfma: implicit-GEMM 3x3 conv, one (ky,kx) tap per blockIdx.y. bf16 parts.
// ---------------------------------------------------------------------------
__global__ __launch_bounds__(256) void conv_mfma_k(
    const ushort_t* __restrict__ Amain,   // [CIp][66][64]
    const ushort_t* __restrict__ Ahalo,   // [CIp][66][66]
    const ushort_t* __restrict__ Wp,      // [9][128][CIp]
    ushort_t* __restrict__ parts,
    int CIp, int ksteps) {
  __shared__ __align__(16) ushort_t Abuf[2][2048];
  const int y   = blockIdx.x;
  const int kk  = blockIdx.y;
  const int ky  = kk / 3, kx = kk - ky * 3;
  const int tid = threadIdx.x;
  const int w   = tid >> 6, l = tid & 63;
  const int lane15 = l & 15, g = l >> 4;
  const int yy1 = y + ky;

  const int ci_l = w * 8 + (l >> 5) * 4 + ((l & 7) >> 1);
  const int m0   = ((l >> 3) & 3) * 16 + (l & 1) * 8;
  const ushort_t* src;
  size_t plane;
  if (kx == 1) { plane = 66 * 64; src = Amain + (size_t)ci_l * plane + yy1 * 64 + m0; }
  else         { plane = 66 * 66; src = Ahalo + (size_t)ci_l * plane + yy1 * 66 + m0 + kx; }

  const ushort_t* wbase = Wp + ((size_t)kk * 128 + w * 32 + lane15) * CIp + g * 8;
  const unsigned tr_base = LDS_U32(&Abuf[0][0]) + (unsigned)(g * 1024 + lane15 * 8);

  f32x4 acc[4][2];
  #pragma unroll
  for (int q = 0; q < 4; ++q) {
    acc[q][0] = (f32x4){0.f, 0.f, 0.f, 0.f};
    acc[q][1] = (f32x4){0.f, 0.f, 0.f, 0.f};
  }

  __builtin_amdgcn_global_load_lds(
      (const __attribute__((address_space(1))) unsigned*)src,
      (__attribute__((address_space(3))) unsigned*)(&Abuf[0][w * 512]), 16, 0, 0);
  __syncthreads();

  for (int s = 0; s < ksteps; ++s) {
    if (s + 1 < ksteps) {
      const ushort_t* srcn = src + (size_t)(s + 1) * 32 * plane;
      __builtin_amdgcn_global_load_lds(
          (const __attribute__((address_space(1))) unsigned*)srcn,
          (__attribute__((address_space(3))) unsigned*)(&Abuf[(s + 1) & 1][w * 512]), 16, 0, 0);
    }
    const ushort_t* wb = wbase + s * 32;
    fragU fb0, fb1;
    fb0.u4 = *(const uint4*)(wb);
    fb1.u4 = *(const uint4*)(wb + 16 * CIp);

    unsigned ta = tr_base + (unsigned)((s & 1) << 12);
    unsigned long long r00, r01, r10, r11, r20, r21, r30, r31;
    asm volatile("ds_read_b64_tr_b16 %0, %1 offset:0"   : "=v"(r00) : "v"(ta));
    asm volatile("ds_read_b64_tr_b16 %0, %1 offset:512" : "=v"(r01) : "v"(ta));
    asm volatile("ds_read_b64_tr_b16 %0, %1 offset:128" : "=v"(r10) : "v"(ta));
    asm volatile("ds_read_b64_tr_b16 %0, %1 offset:640" : "=v"(r11) : "v"(ta));
    asm volatile("ds_read_b64_tr_b16 %0, %1 offset:256" : "=v"(r20) : "v"(ta));
    asm volatile("ds_read_b64_tr_b16 %0, %1 offset:768" : "=v"(r21) : "v"(ta));
    asm volatile("ds_read_b64_tr_b16 %0, %1 offset:384" : "=v"(r30) : "v"(ta));
    asm volatile("ds_read_b64_tr_b16 %0, %1 offset:896" : "=v"(r31) : "v"(ta));
    asm volatile("s_waitcnt lgkmcnt(0)" ::: "memory");
    __builtin_amdgcn_sched_barrier(0);

    fragU fa;
    fa.q[0] = r00; fa.q[1] = r01;
    acc[0][0] = __builtin_amdgcn_mfma_f32_16x16x32_bf16(fa.v, fb0.v, acc[0][0], 0, 0, 0);
    acc[0][1] = __builtin_amdgcn_mfma_f32_16x16x32_bf16(fa.v, fb1.v, acc[0][1], 0, 0, 0);
    fa.q[0] = r10; fa.q[1] = r11;
    acc[1][0] = __builtin_amdgcn_mfma_f32_16x16x32_bf16(fa.v, fb0.v, acc[1][0], 0, 0, 0);
    acc[1][1] = __builtin_amdgcn_mfma_f32_16x16x32_bf16(fa.v, fb1.v, acc[1][1], 0, 0, 0);
    fa.q[0] = r20; fa.q[1] = r21;
    acc[2][0] = __builtin_amdgcn_mfma_f32_16x16x32_bf16(fa.v, fb0.v, acc[2][0], 0, 0, 0);
    acc[2][1] = __builtin_amdgcn_mfma_f32_16x16x32_bf16(fa.v, fb1.v, acc[2][1], 0, 0, 0);
    fa.q[0] = r30; fa.q[1] = r31;
    acc[3][0] = __builtin_amdgcn_mfma_f32_16x16x32_bf16(fa.v, fb0.v, acc[3][0], 0, 0, 0);
    acc[3][1] = __builtin_amdgcn_mfma_f32_16x16x32_bf16(fa.v, fb1.v, acc[3][1], 0, 0, 0);
    __syncthreads();
  }

  ushort_t* pout = parts + (size_t)kk * 524288 + (size_t)(w * 32 + lane15) * 4096
                 + y * 64 + g * 4;
  #pragma unroll
  for (int q = 0; q < 4; ++q) {
    ushort4 p0, p1;
    p0.x = f2bf(acc[q][0][0]); p0.y = f2bf(acc[q][0][1]);
    p0.z = f2bf(acc[q][0][2]); p0.w = f2bf(acc[q][0][3]);
    p1.x = f2bf(acc[q][1][0]); p1.y = f2bf(acc[q][1][1]);
    p1.z = f2bf(acc[q][1][2]); p1.w = f2bf(acc[q][1][3]);
    *(ushort4*)(pout + q * 16)             = p0;
    *(ushort4*)(pout + 16 * 4096 + q * 16) = p1;
  }
}

// ---------------------------------------------------------------------------
// reduce9: out[co][n] = sum_kk bf16 parts (+bias); optional bf16 mirror.
// ---------------------------------------------------------------------------
__global__ __launch_bounds__(256) void reduce9_k(
    const ushort_t* __restrict__ parts, float* __restrict__ out,
    ushort_t* __restrict__ outbf, const float* __restrict__ bias) {
  int n0 = (blockIdx.x * 256 + threadIdx.x) * 8;
  int co = blockIdx.y;
  size_t off = (size_t)co * 4096 + n0;
  float s[8] = {0, 0, 0, 0, 0, 0, 0, 0};
  #pragma unroll
  for (int kk = 0; kk < 9; ++kk) {
    uint4 v = *(const uint4*)(parts + (size_t)kk * 524288 + off);
    s[0] += bf2f(v.x & 0xffffu); s[1] += bf2f(v.x >> 16);
    s[2] += bf2f(v.y & 0xffffu); s[3] += bf2f(v.y >> 16);
    s[4] += bf2f(v.z & 0xffffu); s[5] += bf2f(v.z >> 16);
    s[6] += bf2f(v.w & 0xffffu); s[7] += bf2f(v.w >> 16);
  }
  float b = bias ? bias[co] : 0.f;
  #pragma unroll
  for (int i = 0; i < 8; ++i) s[i] += b;
  f32x4 o0 = {s[0], s[1], s[2], s[3]};
  f32x4 o1 = {s[4], s[5], s[6], s[7]};
  *(f32x4*)(out + off)     = o0;
  *(f32x4*)(out + off + 4) = o1;
  if (outbf) {
    ushort4 b0, b1;
    b0.x = f2bf(s[0]); b0.y = f2bf(s[1]); b0.z = f2bf(s[2]); b0.w = f2bf(s[3]);
    b1.x = f2bf(s[4]); b1.y = f2bf(s[5]); b1.z = f2bf(s[6]); b1.w = f2bf(s[7]);
    *(ushort4*)(outbf + off)     = b0;
    *(ushort4*)(outbf + off + 4) = b1;
  }
}

// ---------------------------------------------------------------------------
// qkv_mfma: 1x1-conv MFMA GEMM. grid (64 pixblk, 6 tiles), block 256.
//   t0/t1: lidQK q/k cols; t2/t3: camQK q/k; t4: camV; t5: lidV.
// A: X bf16 [128ci][4096] staged via global_load_lds + tr-reads (as conv).
// B: Wq [6][128][128]. QK epilogue -> [n][256]; V epilogue -> [128][4096].
// ---------------------------------------------------------------------------
__global__ __launch_bounds__(256) void qkv_mfma_k(
    const ushort_t* __restrict__ lidBF, const ushort_t* __restrict__ camBF,
    const ushort_t* __restrict__ Wq,
    ushort_t* __restrict__ lidQK, ushort_t* __restrict__ camQK,
    ushort_t* __restrict__ camV, ushort_t* __restrict__ lidV) {
  __shared__ __align__(16) ushort_t Abuf[2][2048];
  const int y = blockIdx.x, t = blockIdx.y;
  const ushort_t* X = (t >= 2 && t <= 4) ? camBF : lidBF;
  const int tid = threadIdx.x;
  const int w = tid >> 6, l = tid & 63;
  const int lane15 = l & 15, g = l >> 4;
  const int ci_l = w * 8 + (l >> 5) * 4 + ((l & 7) >> 1);
  const int m0   = ((l >> 3) & 3) * 16 + (l & 1) * 8;
  const ushort_t* src = X + (size_t)ci_l * 4096 + y * 64 + m0;
  const ushort_t* wbase = Wq + (size_t)t * 16384 + (w * 32 + lane15) * 128 + g * 8;
  const unsigned tr_base = LDS_U32(&Abuf[0][0]) + (unsigned)(g * 1024 + lane15 * 8);

  f32x4 acc[4][2];
  #pragma unroll
  for (int q = 0; q < 4; ++q) {
    acc[q][0] = (f32x4){0.f, 0.f, 0.f, 0.f};
    acc[q][1] = (f32x4){0.f, 0.f, 0.f, 0.f};
  }

  __builtin_amdgcn_global_load_lds(
      (const __attribute__((address_space(1))) unsigned*)src,
      (__attribute__((address_space(3))) unsigned*)(&Abuf[0][w * 512]), 16, 0, 0);
  __syncthreads();

  for (int s = 0; s < 4; ++s) {
    if (s < 3) {
      const ushort_t* srcn = src + (size_t)(s + 1) * 32 * 4096;
      __builtin_amdgcn_global_load_lds(
          (const __attribute__((address_space(1))) unsigned*)srcn,
          (__attribute__((address_space(3))) unsigned*)(&Abuf[(s + 1) & 1][w * 512]), 16, 0, 0);
    }
    const ushort_t* wb = wbase + s * 32;
    fragU fb0, fb1;
    fb0.u4 = *(const uint4*)(wb);
    fb1.u4 = *(const uint4*)(wb + 16 * 128);

    unsigned ta = tr_base + (unsigned)((s & 1) << 12);
    unsigned long long r00, r01, r10, r11, r20, r21, r30, r31;
    asm volatile("ds_read_b64_tr_b16 %0, %1 offset:0"   : "=v"(r00) : "v"(ta));
    asm volatile("ds_read_b64_tr_b16 %0, %1 offset:512" : "=v"(r01) : "v"(ta));
    asm volatile("ds_read_b64_tr_b16 %0, %1 offset:128" : "=v"(r10) : "v"(ta));
    asm volatile("ds_read_b64_tr_b16 %0, %1 offset:640" : "=v"(r11) : "v"(ta));
    asm volatile("ds_read_b64_tr_b16 %0, %1 offset:256" : "=v"(r20) : "v"(ta));
    asm volatile("ds_read_b64_tr_b16 %0, %1 offset:768" : "=v"(r21) : "v"(ta));
    asm volatile("ds_read_b64_tr_b16 %0, %1 offset:384" : "=v"(r30) : "v"(ta));
    asm volatile("ds_read_b64_tr_b16 %0, %1 offset:896" : "=v"(r31) : "v"(ta));
    asm volatile("s_waitcnt lgkmcnt(0)" ::: "memory");
    __builtin_amdgcn_sched_barrier(0);

    fragU fa;
    fa.q[0] = r00; fa.q[1] = r01;
    acc[0][0] = __builtin_amdgcn_mfma_f32_16x16x32_bf16(fa.v, fb0.v, acc[0][0], 0, 0, 0);
    acc[0][1] = __builtin_amdgcn_mfma_f32_16x16x32_bf16(fa.v, fb1.v, acc[0][1], 0, 0, 0);
    fa.q[0] = r10; fa.q[1] = r11;
    acc[1][0] = __builtin_amdgcn_mfma_f32_16x16x32_bf16(fa.v, fb0.v, acc[1][0], 0, 0, 0);
    acc[1][1] = __builtin_amdgcn_mfma_f32_16x16x32_bf16(fa.v, fb1.v, acc[1][1], 0, 0, 0);
    fa.q[0] = r20; fa.q[1] = r21;
    acc[2][0] = __builtin_amdgcn_mfma_f32_16x16x32_bf16(fa.v, fb0.v, acc[2][0], 0, 0, 0);
    acc[2][1] = __builtin_amdgcn_mfma_f32_16x16x32_bf16(fa.v, fb1.v, acc[2][1], 0, 0, 0);
    fa.q[0] = r30; fa.q[1] = r31;
    acc[3][0] = __builtin_amdgcn_mfma_f32_16x16x32_bf16(fa.v, fb0.v, acc[3][0], 0, 0, 0);
    acc[3][1] = __builtin_amdgcn_mfma_f32_16x16x32_bf16(fa.v, fb1.v, acc[3][1], 0, 0, 0);
    __syncthreads();
  }

  if (t < 4) {
    ushort_t* dst = (t < 2) ? lidQK : camQK;
    const int colbase = (t & 1) * 128 + w * 32 + lane15;
    #pragma unroll
    for (int q = 0; q < 4; ++q)
      #pragma unroll
      for (int tt = 0; tt < 2; ++tt)
        #pragma unroll
        for (int r = 0; r < 4; ++r) {
          int n = y * 64 + q * 16 + g * 4 + r;
          dst[(size_t)n * 256 + colbase + tt * 16] = f2bf(acc[q][tt][r]);
        }
  } else {
    ushort_t* dst = (t == 4) ? camV : lidV;
    ushort_t* pout = dst + (size_t)(w * 32 + lane15) * 4096 + y * 64 + g * 4;
    #pragma unroll
    for (int q = 0; q < 4; ++q) {
      ushort4 p0, p1;
      p0.x = f2bf(acc[q][0][0]); p0.y = f2bf(acc[q][0][1]);
      p0.z = f2bf(acc[q][0][2]); p0.w = f2bf(acc[q][0][3]);
      p1.x = f2bf(acc[q][1][0]); p1.y = f2bf(acc[q][1][1]);
      p1.z = f2bf(acc[q][1][2]); p1.w = f2bf(acc[q][1][3]);
      *(ushort4*)(pout + q * 16)             = p0;
      *(ushort4*)(pout + 16 * 4096 + q * 16) = p1;
    }
  }
}

// ---------------------------------------------------------------------------
// flash attention v4: Vt XOR-rotate swizzle (conflict-free V reads/writes),
// wave-global deferred max (shfl-free common path), lrun via ones-column MFMA.
// grid (64 qblk, 4 h, 4 = attn*2+half), block 256 = 4 waves; 2048 keys/block.
// ---------------------------------------------------------------------------
__global__ __launch_bounds__(256) void flash_attn_mfma(
    const ushort_t* __restrict__ lidQK, const ushort_t* __restrict__ camQK,
    const ushort_t* __restrict__ camV, const ushort_t* __restrict__ lidV,
    ushort_t* __restrict__ OP, float2* __restrict__ ML) {
  const int i0    = blockIdx.x * 64;
  const int h     = blockIdx.y;
  const int attn  = blockIdx.z >> 1;
  const int half  = blockIdx.z & 1;
  const int kbase = half * 2048;
  const ushort_t* QK = attn ? camQK : lidQK;

  __shared__ __align__(16) ushort_t Ks[2][64 * 40];
  __shared__ __align__(16) ushort_t Vt[2][64 * 72];
  __shared__ __align__(16) ushort_t Ps[64 * 72];

  const int tid = threadIdx.x;
  const int w = tid >> 6, l = tid & 63;
  const int m = l & 15, g = l >> 4;
  const int qrow = tid >> 2, qpart = tid & 3;
  const int vrow = tid >> 3, vj = tid & 7;
  // V staging swizzle: logical chunk c=(vj-3*vrow)&7 stored at (vj-vrow)&7
  const int vc_src = (vj - 3 * vrow) & 7;
  const int vc_sto = ((vj - vrow) & 7);

  const ushort_t* Kp = QK + (size_t)(kbase + qrow) * 256 + 128 + h * 32 + qpart * 8;
  const ushort_t* Vc = camV + (size_t)(h * 32 + (vrow & 31)) * N_PIX + kbase + vc_src * 8;
  const ushort_t* Vl = lidV + (size_t)(h * 32 + (vrow & 31)) * N_PIX + kbase + vc_src * 8;

  uint4 q4  = *(const uint4*)(QK + (size_t)(i0 + qrow) * 256 + h * 32 + qpart * 8);
  uint4 k4  = *(const uint4*)Kp;
  uint4 vc4 = *(const uint4*)Vc;
  uint4 vl4 = *(const uint4*)Vl;
  *(uint4*)(&Ps[qrow * 40 + qpart * 8]) = q4;
  __syncthreads();
  bf16x8 qfrag = *(const bf16x8*)(&Ps[(w * 16 + m) * 40 + g * 8]);
  *(uint4*)(&Ks[0][qrow * 40 + qpart * 8]) = k4;
  *(uint4*)(&Vt[0][vrow * 72 + vc_sto * 8]) = vc4;
  *(uint4*)(&Vt[0][(vrow + 32) * 72 + vc_sto * 8]) = vl4;
  __syncthreads();

  fragU ones;
  #pragma unroll
  for (int j = 0; j < 8; ++j) ones.us[j] = 0x3F80;   // bf16 1.0

  f32x4 Oacc[4];
  #pragma unroll
  for (int t = 0; t < 4; ++t) Oacc[t] = (f32x4){0.f, 0.f, 0.f, 0.f};
  f32x4 lacc = (f32x4){0.f, 0.f, 0.f, 0.f};
  float mrun = -1e30f;                                // wave-uniform

  // V read chunk positions (swizzled): chunk' = (ks*4+g + 2*m) & 7
  const int vcs0 = ((g + 2 * m) & 7) * 8;
  const int vcs1 = ((4 + g + 2 * m) & 7) * 8;

  for (int it = 0; it < 32; ++it) {
    const int cur = it & 1, nxt = cur ^ 1;
    const bool more = (it + 1) < 32;
    uint4 kn, vcn, vln;
    if (more) {
      kn  = *(const uint4*)(Kp + (size_t)(it + 1) * 16384);
      vcn = *(const uint4*)(Vc + (it + 1) * 64);
      vln = *(const uint4*)(Vl + (it + 1) * 64);
    }

    // S^T = K Q^T : lane (m,g) reg r -> S[q=w*16+m][k=nb*16+g*4+r]
    f32x4 S[4];
    __builtin_amdgcn_s_setprio(1);
    #pragma unroll
    for (int nb = 0; nb < 4; ++nb) {
      bf16x8 kb = *(const bf16x8*)(&Ks[cur][(nb * 16 + m) * 40 + g * 8]);
      f32x4 z = (f32x4){0.f, 0.f, 0.f, 0.f};
      S[nb] = __builtin_amdgcn_mfma_f32_16x16x32_bf16(kb, qfrag, z, 0, 0, 0);
    }
    __builtin_amdgcn_s_setprio(0);

    // cheap guard; full reduce + uniform rescale only when max grows
    float mx = fmaxf(fmaxf(fmaxf(S[0][0], S[0][1]), fmaxf(S[0][2], S[0][3])),
                     fmaxf(fmaxf(S[1][0], S[1][1]), fmaxf(S[1][2], S[1][3])));
    mx = fmaxf(mx, fmaxf(fmaxf(fmaxf(S[2][0], S[2][1]), fmaxf(S[2][2], S[2][3])),
                         fmaxf(fmaxf(S[3][0], S[3][1]), fmaxf(S[3][2], S[3][3]))));
    if (__any(mx > mrun + 6.f)) {
      float gm = mx;
      gm = fmaxf(gm, __shfl_xor(gm, 1));
      gm = fmaxf(gm, __shfl_xor(gm, 2));
      gm = fmaxf(gm, __shfl_xor(gm, 4));
      gm = fmaxf(gm, __shfl_xor(gm, 8));
      gm = fmaxf(gm, __shfl_xor(gm, 16));
      gm = fmaxf(gm, __shfl_xor(gm, 32));
      if (gm > mrun) {
        float corr = __builtin_amdgcn_exp2f(mrun - gm);
        #pragma unroll
        for (int t = 0; t < 4; ++t)
          #pragma unroll
          for (int r = 0; r < 4; ++r) Oacc[t][r] *= corr;
        #pragma unroll
        for (int r = 0; r < 4; ++r) lacc[r] *= corr;
        mrun = gm;
      }
    }

    #pragma unroll
    for (int nb = 0; nb < 4; ++nb)
      #pragma unroll
      for (int r = 0; r < 4; ++r)
        S[nb][r] = __builtin_amdgcn_exp2f(S[nb][r] - mrun);

    // P -> Ps bf16 via packed converts (wave-private rows)
    #pragma unroll
    for (int nb = 0; nb < 4; ++nb) {
      unsigned d0, d1;
      asm("v_cvt_pk_bf16_f32 %0, %1, %2" : "=v"(d0) : "v"(S[nb][0]), "v"(S[nb][1]));
      asm("v_cvt_pk_bf16_f32 %0, %1, %2" : "=v"(d1) : "v"(S[nb][2]), "v"(S[nb][3]));
      uint2 dd; dd.x = d0; dd.y = d1;
      *(uint2*)(&Ps[(w * 16 + m) * 72 + nb * 16 + g * 4]) = dd;
    }

    __builtin_amdgcn_s_setprio(1);
    #pragma unroll
    for (int ks = 0; ks < 2; ++ks) {
      bf16x8 pa = *(const bf16x8*)(&Ps[(w * 16 + m) * 72 + ks * 32 + g * 8]);
      const int vcs = ks ? vcs1 : vcs0;
      #pragma unroll
      for (int t = 0; t < 4; ++t) {
        bf16x8 vb = *(const bf16x8*)(&Vt[cur][(t * 16 + m) * 72 + vcs]);
        Oacc[t] = __builtin_amdgcn_mfma_f32_16x16x32_bf16(pa, vb, Oacc[t], 0, 0, 0);
      }
      lacc = __builtin_amdgcn_mfma_f32_16x16x32_bf16(pa, ones.v, lacc, 0, 0, 0);
    }
    __builtin_amdgcn_s_setprio(0);

    if (more) {
      *(uint4*)(&Ks[nxt][qrow * 40 + qpart * 8]) = kn;
      *(uint4*)(&Vt[nxt][vrow * 72 + vc_sto * 8]) = vcn;
      *(uint4*)(&Vt[nxt][(vrow + 32) * 72 + vc_sto * 8]) = vln;
    }
    __syncthreads();
  }

  // epilogue: unnormalized bf16 partials [a/half][v][n][d]; ML per q-row
  ushort_t* OPc = OP + (size_t)((attn * 2 + half) * 2 + 0) * 4096 * 128;
  ushort_t* OPl = OP + (size_t)((attn * 2 + half) * 2 + 1) * 4096 * 128;
  #pragma unroll
  for (int t = 0; t < 4; ++t) {
    ushort_t* Ob = (t < 2) ? OPc : OPl;
    int d = h * 32 + (t & 1) * 16 + m;
    #pragma unroll
    for (int r = 0; r < 4; ++r) {
      int n = i0 + w * 16 + g * 4 + r;
      Ob[(size_t)n * 128 + d] = f2bf(Oacc[t][r]);
    }
  }
  if (m == 0) {
    #pragma unroll
    for (int r = 0; r < 4; ++r) {
      float2 v; v.x = mrun; v.y = lacc[r];
      ML[(size_t)(attn * 2 + half) * 4096 + i0 + w * 16 + g * 4 + r] = v;
    }
  }
}

// ---------------------------------------------------------------------------
// proj_mfma: key-split combine + projection GEMM + residual + bias
// -> padded bf16 fuser-conv inputs. grid (64 nblk, 4 ot), block 256.
// ---------------------------------------------------------------------------
__global__ __launch_bounds__(256) void proj_mfma_k(
    const ushort_t* __restrict__ OP, const float2* __restrict__ ML,
    const ushort_t* __restrict__ Wlid, const ushort_t* __restrict__ Wcam,
    const float* __restrict__ cam_enc, const float* __restrict__ lidar_bev,
    const float* __restrict__ cam_proj_b, const float* __restrict__ lid_proj_b,
    ushort_t* __restrict__ fm, ushort_t* __restrict__ fh) {
  const int n0 = blockIdx.x * 64;
  const int ot = blockIdx.y;
  const int attn = (ot == 0 || ot == 2) ? 1 : 0;
  const int vt = ot >> 1;
  const int tid = threadIdx.x;
  const int w = tid >> 6, l = tid & 63;
  const int m = l & 15, g = l >> 4;

  const ushort_t* Oa = OP + (size_t)((attn * 2 + 0) * 2 + vt) * 4096 * 128;
  const ushort_t* Ob = OP + (size_t)((attn * 2 + 1) * 2 + vt) * 4096 * 128;
  const float2* MLa = ML + (size_t)(attn * 2 + 0) * 4096;
  const float2* MLb = ML + (size_t)(attn * 2 + 1) * 4096;

  const int arow = n0 + w * 16 + m;
  float2 mla = MLa[arow], mlb = MLb[arow];
  float M  = fmaxf(mla.x, mlb.x);
  float wa = __builtin_amdgcn_exp2f(mla.x - M);
  float wb = __builtin_amdgcn_exp2f(mlb.x - M);
  float dn = wa * mla.y + wb * mlb.y;
  float aa = wa / dn, ab = wb / dn;

  fragU afr[4];
  #pragma unroll
  for (int s = 0; s < 4; ++s) {
    fragU xa, xb;
    xa.u4 = *(const uint4*)(Oa + (size_t)arow * 128 + s * 32 + g * 8);
    xb.u4 = *(const uint4*)(Ob + (size_t)arow * 128 + s * 32 + g * 8);
    #pragma unroll
    for (int j = 0; j < 8; ++j)
      afr[s].us[j] = f2bf(aa * bf2f(xa.us[j]) + ab * bf2f(xb.us[j]));
  }

  const ushort_t* W = (ot == 1) ? Wcam : Wlid;
  f32x4 acc[8];
  #pragma unroll
  for (int t = 0; t < 8; ++t) acc[t] = (f32x4){0.f, 0.f, 0.f, 0.f};
  #pragma unroll
  for (int s = 0; s < 4; ++s) {
    #pragma unroll
    for (int t = 0; t < 8; ++t) {
      fragU bfr;
      bfr.u4 = *(const uint4*)(W + (size_t)(t * 16 + m) * 128 + s * 32 + g * 8);
      acc[t] = __builtin_amdgcn_mfma_f32_16x16x32_bf16(afr[s].v, bfr.v, acc[t], 0, 0, 0);
    }
  }

  const float* res  = (ot < 2) ? cam_enc : lidar_bev;
  const float* bias = (ot == 1) ? cam_proj_b : lid_proj_b;
  const int doff = ot * 126;
  #pragma unroll
  for (int t = 0; t < 8; ++t) {
    int co = t * 16 + m;
    if (co < 126) {
      float b = bias[co];
      #pragma unroll
      for (int r = 0; r < 4; ++r) {
        int n = n0 + w * 16 + g * 4 + r;
        float v = acc[t][r] + res[(size_t)co * N_PIX + n] + b;
        unsigned short bf = f2bf(v);
        int y = n >> 6, x = n & 63;
        fm[(doff + co) * 4224 + (y + 1) * 64 + x]      = bf;
        fh[(doff + co) * 4356 + (y + 1) * 66 + x + 1]  = bf;
      }
    }
  }
}

// ---------------------------------------------------------------------------
extern "C" void kernel_launch(void* const* d_in, const int* in_sizes, int n_in,
                              void* d_out, int out_size, void* d_ws, size_t ws_size,
                              hipStream_t stream) {
  (void)in_sizes; (void)n_in; (void)out_size; (void)ws_size;
  const float* lidar_bev  = (const float*)d_in[0];
  const float* cam_bev    = (const float*)d_in[1];
  const float* cam_enc_w  = (const float*)d_in[2];
  const float* cam_enc_b  = (const float*)d_in[3];
  const float* cam_v_w    = (const float*)d_in[4];
  const float* cam_qk_w   = (const float*)d_in[5];
  const float* cam_proj_w = (const float*)d_in[6];
  const float* cam_proj_b = (const float*)d_in[7];
  const float* lid_v_w    = (const float*)d_in[8];
  const float* lid_qk_w   = (const float*)d_in[9];
  const float* lid_proj_w = (const float*)d_in[10];
  const float* lid_proj_b = (const float*)d_in[11];
  const float* fuser_w    = (const float*)d_in[12];
  float* out = (float*)d_out;

  char* p = (char*)d_ws;
  ushort_t* arena = (ushort_t*)p;                  // 9 x [128][4096] bf16 (conv)
  ushort_t* OP    = (ushort_t*)p;                  // [2a][2h][2v][4096][128] bf16, aliased
  float2*   ML    = (float2*)(p + 8388608);        // [2a][2h][4096] float2
  ushort_t* lidQK = (ushort_t*)(p + 9437184);      // [4096][256] bf16
  ushort_t* camQK = (ushort_t*)(p + 11534336);
  ushort_t* camV  = (ushort_t*)(p + 13631488);     // [128][4096] bf16
  ushort_t* lidV  = (ushort_t*)(p + 14680064);
  float*    cam_enc = (float*)(p + 15728640);      // [126][4096] f32
  ushort_t* Wp_c    = (ushort_t*)(p + 17793024);   // [9][128][96]
  ushort_t* Wp_f    = (ushort_t*)(p + 18014208);   // [9][128][512]
  ushort_t* Wp_lid  = (ushort_t*)(p + 19193856);   // [128][128]
  ushort_t* Wp_cam  = (ushort_t*)(p + 19226624);   // [128][128]
  ushort_t* Wq      = (ushort_t*)(p + 19259392);   // [6][128][128]
  ushort_t* lidBF   = (ushort_t*)(p + 19456000);   // [128][4096] (126 used)
  ushort_t* camBF   = (ushort_t*)(p + 20504576);   // [128][4096] (126 used)
  ushort_t* camBF_m = (ushort_t*)(p + 21553152);   // [96][66][64]
  ushort_t* camBF_h = (ushort_t*)(p + 22364160);   // [96][66][66]
  ushort_t* fusBF_m = (ushort_t*)(p + 23200512);   // [512][66][64]
  ushort_t* fusBF_h = (ushort_t*)(p + 27525888);   // [512][66][66] (end 31986432)

  zero_span_k<<<2548, 256, 0, stream>>>((uint4*)(p + 21553152), 652080);
  pack_w_k<<<3248, 256, 0, stream>>>(cam_enc_w, fuser_w, lid_proj_w, cam_proj_w,
                                     lid_qk_w, cam_qk_w, cam_v_w, lid_v_w,
                                     Wp_c, Wp_f, Wp_lid, Wp_cam, Wq);
  convert_in_k<<<3296, 256, 0, stream>>>(cam_bev, lidar_bev, camBF_m, camBF_h, lidBF);

  conv_mfma_k<<<dim3(64, 9), 256, 0, stream>>>(camBF_m, camBF_h, Wp_c, arena, 96, 3);
  reduce9_k<<<dim3(2, 126), 256, 0, stream>>>(arena, cam_enc, camBF, cam_enc_b);

  qkv_mfma_k<<<dim3(64, 6), 256, 0, stream>>>(lidBF, camBF, Wq, lidQK, camQK, camV, lidV);
  flash_attn_mfma<<<dim3(64, 4, 4), 256, 0, stream>>>(lidQK, camQK, camV, lidV, OP, ML);
  proj_mfma_k<<<dim3(64, 4), 256, 0, stream>>>(OP, ML, Wp_lid, Wp_cam, cam_enc, lidar_bev,
                                               cam_proj_b, lid_proj_b, fusBF_m, fusBF_h);

  conv_mfma_k<<<dim3(64, 9), 256, 0, stream>>>(fusBF_m, fusBF_h, Wp_f, arena, 512, 16);
  reduce9_k<<<dim3(2, 126), 256, 0, stream>>>(arena, out, nullptr, nullptr);
}

// Round 6
// 117.236 us; speedup vs baseline: 2.2890x; 1.0936x over previous
//
#include <hip/hip_runtime.h>
#include <hip/hip_bf16.h>

typedef unsigned short ushort_t;
using f32x4  = __attribute__((ext_vector_type(4))) float;
using f32x16 = __attribute__((ext_vector_type(16))) float;
using bf16x8 = __attribute__((ext_vector_type(8))) short;
typedef unsigned uint2v __attribute__((ext_vector_type(2)));

#define N_PIX 4096

static __device__ __forceinline__ unsigned short f2bf(float f) {
  unsigned int u = __builtin_bit_cast(unsigned int, f);
  u += 0x7FFFu + ((u >> 16) & 1u);   // round-to-nearest-even
  return (unsigned short)(u >> 16);
}
static __device__ __forceinline__ float bf2f(unsigned int us) {
  return __builtin_bit_cast(float, us << 16);
}

typedef union {
  uint4 u4;
  unsigned u[4];
  unsigned long long q[2];
  bf16x8 v;
  unsigned short us[8];
} fragU;

#define LDS_U32(p) ((unsigned)(uintptr_t)((__attribute__((address_space(3))) void*)(p)))

// ---------------------------------------------------------------------------
__global__ __launch_bounds__(256) void zero_span_k(uint4* __restrict__ p, int n16) {
  int i = blockIdx.x * 256 + threadIdx.x;
  if (i < n16) p[i] = (uint4){0u, 0u, 0u, 0u};
}

// ---------------------------------------------------------------------------
// pack_w: bf16 weights: Wp_c [9][128][96], Wp_f [9][128][512],
//   Wp_lid/Wp_cam [128][128] proj, Wq [6][128][128] qkv (Q rows pre-scaled).
// ---------------------------------------------------------------------------
__global__ __launch_bounds__(256) void pack_w_k(
    const float* __restrict__ cam_enc_w, const float* __restrict__ fuser_w,
    const float* __restrict__ lid_proj_w, const float* __restrict__ cam_proj_w,
    const float* __restrict__ lid_qk_w, const float* __restrict__ cam_qk_w,
    const float* __restrict__ cam_v_w, const float* __restrict__ lid_v_w,
    ushort_t* __restrict__ Wp_c, ushort_t* __restrict__ Wp_f,
    ushort_t* __restrict__ Wp_lid, ushort_t* __restrict__ Wp_cam,
    ushort_t* __restrict__ Wq) {
  const float QSCALE = 0.08908708063747479f * 1.4426950408889634f;
  int idx = blockIdx.x * 256 + threadIdx.x;
  if (idx < 110592) {                     // 9*128*96
    int kk = idx / 12288, r = idx % 12288;
    int co = r / 96, ci = r % 96;
    float v = (co < 126 && ci < 80) ? cam_enc_w[(co * 80 + ci) * 9 + kk] : 0.f;
    Wp_c[idx] = f2bf(v);
  } else if (idx < 700416) {              // 9*128*512
    int j = idx - 110592;
    int kk = j / 65536, r = j % 65536;
    int co = r / 512, ci = r % 512;
    float v = (co < 126 && ci < 504) ? fuser_w[(co * 504 + ci) * 9 + kk] : 0.f;
    Wp_f[j] = f2bf(v);
  } else if (idx < 716800) {              // 128*128
    int j = idx - 700416;
    int co = j >> 7, k = j & 127;
    Wp_lid[j] = f2bf(co < 126 ? lid_proj_w[co * 128 + k] : 0.f);
  } else if (idx < 733184) {
    int j = idx - 716800;
    int co = j >> 7, k = j & 127;
    Wp_cam[j] = f2bf(co < 126 ? cam_proj_w[co * 128 + k] : 0.f);
  } else if (idx < 831488) {              // 6*128*128
    int j = idx - 733184;
    int t = j >> 14, r = j & 16383;
    int row = r >> 7, ci = r & 127;
    float v = 0.f;
    if (ci < 126) {
      if (t == 0)      v = lid_qk_w[row * 126 + ci] * QSCALE;
      else if (t == 1) v = lid_qk_w[(128 + row) * 126 + ci];
      else if (t == 2) v = cam_qk_w[row * 126 + ci] * QSCALE;
      else if (t == 3) v = cam_qk_w[(128 + row) * 126 + ci];
      else if (t == 4) v = cam_v_w[row * 126 + ci];
      else             v = lid_v_w[row * 126 + ci];
    }
    Wq[j] = f2bf(v);
  }
}

// ---------------------------------------------------------------------------
__global__ __launch_bounds__(256) void convert_in_k(
    const float* __restrict__ cam, const float* __restrict__ lidar,
    ushort_t* __restrict__ m, ushort_t* __restrict__ h,
    ushort_t* __restrict__ lidBF) {
  int idx = blockIdx.x * 256 + threadIdx.x;
  if (idx < 327680) {                         // 80*4096
    int ch = idx >> 12, n = idx & 4095;
    int y = n >> 6, x = n & 63;
    unsigned short b = f2bf(cam[idx]);
    m[ch * 4224 + (y + 1) * 64 + x] = b;
    h[ch * 4356 + (y + 1) * 66 + (x + 1)] = b;
  } else {
    int j = idx - 327680;                     // 126*4096
    if (j < 516096) lidBF[j] = f2bf(lidar[j]);
  }
}

// ---------------------------------------------------------------------------
// conv_mfma: implicit-GEMM 3x3 conv, one (ky,kx) tap per blockIdx.y. bf16 parts.
// ---------------------------------------------------------------------------
__global__ __launch_bounds__(256) void conv_mfma_k(
    const ushort_t* __restrict__ Amain,   // [CIp][66][64]
    const ushort_t* __restrict__ Ahalo,   // [CIp][66][66]
    const ushort_t* __restrict__ Wp,      // [9][128][CIp]
    ushort_t* __restrict__ parts,
    int CIp, int ksteps) {
  __shared__ __align__(16) ushort_t Abuf[2][2048];
  const int y   = blockIdx.x;
  const int kk  = blockIdx.y;
  const int ky  = kk / 3, kx = kk - ky * 3;
  const int tid = threadIdx.x;
  const int w   = tid >> 6, l = tid & 63;
  const int lane15 = l & 15, g = l >> 4;
  const int yy1 = y + ky;

  const int ci_l = w * 8 + (l >> 5) * 4 + ((l & 7) >> 1);
  const int m0   = ((l >> 3) & 3) * 16 + (l & 1) * 8;
  const ushort_t* src;
  size_t plane;
  if (kx == 1) { plane = 66 * 64; src = Amain + (size_t)ci_l * plane + yy1 * 64 + m0; }
  else         { plane = 66 * 66; src = Ahalo + (size_t)ci_l * plane + yy1 * 66 + m0 + kx; }

  const ushort_t* wbase = Wp + ((size_t)kk * 128 + w * 32 + lane15) * CIp + g * 8;
  const unsigned tr_base = LDS_U32(&Abuf[0][0]) + (unsigned)(g * 1024 + lane15 * 8);

  f32x4 acc[4][2];
  #pragma unroll
  for (int q = 0; q < 4; ++q) {
    acc[q][0] = (f32x4){0.f, 0.f, 0.f, 0.f};
    acc[q][1] = (f32x4){0.f, 0.f, 0.f, 0.f};
  }

  __builtin_amdgcn_global_load_lds(
      (const __attribute__((address_space(1))) unsigned*)src,
      (__attribute__((address_space(3))) unsigned*)(&Abuf[0][w * 512]), 16, 0, 0);
  __syncthreads();

  for (int s = 0; s < ksteps; ++s) {
    if (s + 1 < ksteps) {
      const ushort_t* srcn = src + (size_t)(s + 1) * 32 * plane;
      __builtin_amdgcn_global_load_lds(
          (const __attribute__((address_space(1))) unsigned*)srcn,
          (__attribute__((address_space(3))) unsigned*)(&Abuf[(s + 1) & 1][w * 512]), 16, 0, 0);
    }
    const ushort_t* wb = wbase + s * 32;
    fragU fb0, fb1;
    fb0.u4 = *(const uint4*)(wb);
    fb1.u4 = *(const uint4*)(wb + 16 * CIp);

    unsigned ta = tr_base + (unsigned)((s & 1) << 12);
    unsigned long long r00, r01, r10, r11, r20, r21, r30, r31;
    asm volatile("ds_read_b64_tr_b16 %0, %1 offset:0"   : "=v"(r00) : "v"(ta));
    asm volatile("ds_read_b64_tr_b16 %0, %1 offset:512" : "=v"(r01) : "v"(ta));
    asm volatile("ds_read_b64_tr_b16 %0, %1 offset:128" : "=v"(r10) : "v"(ta));
    asm volatile("ds_read_b64_tr_b16 %0, %1 offset:640" : "=v"(r11) : "v"(ta));
    asm volatile("ds_read_b64_tr_b16 %0, %1 offset:256" : "=v"(r20) : "v"(ta));
    asm volatile("ds_read_b64_tr_b16 %0, %1 offset:768" : "=v"(r21) : "v"(ta));
    asm volatile("ds_read_b64_tr_b16 %0, %1 offset:384" : "=v"(r30) : "v"(ta));
    asm volatile("ds_read_b64_tr_b16 %0, %1 offset:896" : "=v"(r31) : "v"(ta));
    asm volatile("s_waitcnt lgkmcnt(0)" ::: "memory");
    __builtin_amdgcn_sched_barrier(0);

    fragU fa;
    fa.q[0] = r00; fa.q[1] = r01;
    acc[0][0] = __builtin_amdgcn_mfma_f32_16x16x32_bf16(fa.v, fb0.v, acc[0][0], 0, 0, 0);
    acc[0][1] = __builtin_amdgcn_mfma_f32_16x16x32_bf16(fa.v, fb1.v, acc[0][1], 0, 0, 0);
    fa.q[0] = r10; fa.q[1] = r11;
    acc[1][0] = __builtin_amdgcn_mfma_f32_16x16x32_bf16(fa.v, fb0.v, acc[1][0], 0, 0, 0);
    acc[1][1] = __builtin_amdgcn_mfma_f32_16x16x32_bf16(fa.v, fb1.v, acc[1][1], 0, 0, 0);
    fa.q[0] = r20; fa.q[1] = r21;
    acc[2][0] = __builtin_amdgcn_mfma_f32_16x16x32_bf16(fa.v, fb0.v, acc[2][0], 0, 0, 0);
    acc[2][1] = __builtin_amdgcn_mfma_f32_16x16x32_bf16(fa.v, fb1.v, acc[2][1], 0, 0, 0);
    fa.q[0] = r30; fa.q[1] = r31;
    acc[3][0] = __builtin_amdgcn_mfma_f32_16x16x32_bf16(fa.v, fb0.v, acc[3][0], 0, 0, 0);
    acc[3][1] = __builtin_amdgcn_mfma_f32_16x16x32_bf16(fa.v, fb1.v, acc[3][1], 0, 0, 0);
    __syncthreads();
  }

  ushort_t* pout = parts + (size_t)kk * 524288 + (size_t)(w * 32 + lane15) * 4096
                 + y * 64 + g * 4;
  #pragma unroll
  for (int q = 0; q < 4; ++q) {
    ushort4 p0, p1;
    p0.x = f2bf(acc[q][0][0]); p0.y = f2bf(acc[q][0][1]);
    p0.z = f2bf(acc[q][0][2]); p0.w = f2bf(acc[q][0][3]);
    p1.x = f2bf(acc[q][1][0]); p1.y = f2bf(acc[q][1][1]);
    p1.z = f2bf(acc[q][1][2]); p1.w = f2bf(acc[q][1][3]);
    *(ushort4*)(pout + q * 16)             = p0;
    *(ushort4*)(pout + 16 * 4096 + q * 16) = p1;
  }
}

// ---------------------------------------------------------------------------
// reduce9: out[co][n] = sum_kk bf16 parts (+bias); optional bf16 mirror.
// ---------------------------------------------------------------------------
__global__ __launch_bounds__(256) void reduce9_k(
    const ushort_t* __restrict__ parts, float* __restrict__ out,
    ushort_t* __restrict__ outbf, const float* __restrict__ bias) {
  int n0 = (blockIdx.x * 256 + threadIdx.x) * 8;
  int co = blockIdx.y;
  size_t off = (size_t)co * 4096 + n0;
  float s[8] = {0, 0, 0, 0, 0, 0, 0, 0};
  #pragma unroll
  for (int kk = 0; kk < 9; ++kk) {
    uint4 v = *(const uint4*)(parts + (size_t)kk * 524288 + off);
    s[0] += bf2f(v.x & 0xffffu); s[1] += bf2f(v.x >> 16);
    s[2] += bf2f(v.y & 0xffffu); s[3] += bf2f(v.y >> 16);
    s[4] += bf2f(v.z & 0xffffu); s[5] += bf2f(v.z >> 16);
    s[6] += bf2f(v.w & 0xffffu); s[7] += bf2f(v.w >> 16);
  }
  float b = bias ? bias[co] : 0.f;
  #pragma unroll
  for (int i = 0; i < 8; ++i) s[i] += b;
  f32x4 o0 = {s[0], s[1], s[2], s[3]};
  f32x4 o1 = {s[4], s[5], s[6], s[7]};
  *(f32x4*)(out + off)     = o0;
  *(f32x4*)(out + off + 4) = o1;
  if (outbf) {
    ushort4 b0, b1;
    b0.x = f2bf(s[0]); b0.y = f2bf(s[1]); b0.z = f2bf(s[2]); b0.w = f2bf(s[3]);
    b1.x = f2bf(s[4]); b1.y = f2bf(s[5]); b1.z = f2bf(s[6]); b1.w = f2bf(s[7]);
    *(ushort4*)(outbf + off)     = b0;
    *(ushort4*)(outbf + off + 4) = b1;
  }
}

// ---------------------------------------------------------------------------
// qkv_mfma: 1x1-conv MFMA GEMM. grid (64 pixblk, 6 tiles), block 256.
// ---------------------------------------------------------------------------
__global__ __launch_bounds__(256) void qkv_mfma_k(
    const ushort_t* __restrict__ lidBF, const ushort_t* __restrict__ camBF,
    const ushort_t* __restrict__ Wq,
    ushort_t* __restrict__ lidQK, ushort_t* __restrict__ camQK,
    ushort_t* __restrict__ camV, ushort_t* __restrict__ lidV) {
  __shared__ __align__(16) ushort_t Abuf[2][2048];
  const int y = blockIdx.x, t = blockIdx.y;
  const ushort_t* X = (t >= 2 && t <= 4) ? camBF : lidBF;
  const int tid = threadIdx.x;
  const int w = tid >> 6, l = tid & 63;
  const int lane15 = l & 15, g = l >> 4;
  const int ci_l = w * 8 + (l >> 5) * 4 + ((l & 7) >> 1);
  const int m0   = ((l >> 3) & 3) * 16 + (l & 1) * 8;
  const ushort_t* src = X + (size_t)ci_l * 4096 + y * 64 + m0;
  const ushort_t* wbase = Wq + (size_t)t * 16384 + (w * 32 + lane15) * 128 + g * 8;
  const unsigned tr_base = LDS_U32(&Abuf[0][0]) + (unsigned)(g * 1024 + lane15 * 8);

  f32x4 acc[4][2];
  #pragma unroll
  for (int q = 0; q < 4; ++q) {
    acc[q][0] = (f32x4){0.f, 0.f, 0.f, 0.f};
    acc[q][1] = (f32x4){0.f, 0.f, 0.f, 0.f};
  }

  __builtin_amdgcn_global_load_lds(
      (const __attribute__((address_space(1))) unsigned*)src,
      (__attribute__((address_space(3))) unsigned*)(&Abuf[0][w * 512]), 16, 0, 0);
  __syncthreads();

  for (int s = 0; s < 4; ++s) {
    if (s < 3) {
      const ushort_t* srcn = src + (size_t)(s + 1) * 32 * 4096;
      __builtin_amdgcn_global_load_lds(
          (const __attribute__((address_space(1))) unsigned*)srcn,
          (__attribute__((address_space(3))) unsigned*)(&Abuf[(s + 1) & 1][w * 512]), 16, 0, 0);
    }
    const ushort_t* wb = wbase + s * 32;
    fragU fb0, fb1;
    fb0.u4 = *(const uint4*)(wb);
    fb1.u4 = *(const uint4*)(wb + 16 * 128);

    unsigned ta = tr_base + (unsigned)((s & 1) << 12);
    unsigned long long r00, r01, r10, r11, r20, r21, r30, r31;
    asm volatile("ds_read_b64_tr_b16 %0, %1 offset:0"   : "=v"(r00) : "v"(ta));
    asm volatile("ds_read_b64_tr_b16 %0, %1 offset:512" : "=v"(r01) : "v"(ta));
    asm volatile("ds_read_b64_tr_b16 %0, %1 offset:128" : "=v"(r10) : "v"(ta));
    asm volatile("ds_read_b64_tr_b16 %0, %1 offset:640" : "=v"(r11) : "v"(ta));
    asm volatile("ds_read_b64_tr_b16 %0, %1 offset:256" : "=v"(r20) : "v"(ta));
    asm volatile("ds_read_b64_tr_b16 %0, %1 offset:768" : "=v"(r21) : "v"(ta));
    asm volatile("ds_read_b64_tr_b16 %0, %1 offset:384" : "=v"(r30) : "v"(ta));
    asm volatile("ds_read_b64_tr_b16 %0, %1 offset:896" : "=v"(r31) : "v"(ta));
    asm volatile("s_waitcnt lgkmcnt(0)" ::: "memory");
    __builtin_amdgcn_sched_barrier(0);

    fragU fa;
    fa.q[0] = r00; fa.q[1] = r01;
    acc[0][0] = __builtin_amdgcn_mfma_f32_16x16x32_bf16(fa.v, fb0.v, acc[0][0], 0, 0, 0);
    acc[0][1] = __builtin_amdgcn_mfma_f32_16x16x32_bf16(fa.v, fb1.v, acc[0][1], 0, 0, 0);
    fa.q[0] = r10; fa.q[1] = r11;
    acc[1][0] = __builtin_amdgcn_mfma_f32_16x16x32_bf16(fa.v, fb0.v, acc[1][0], 0, 0, 0);
    acc[1][1] = __builtin_amdgcn_mfma_f32_16x16x32_bf16(fa.v, fb1.v, acc[1][1], 0, 0, 0);
    fa.q[0] = r20; fa.q[1] = r21;
    acc[2][0] = __builtin_amdgcn_mfma_f32_16x16x32_bf16(fa.v, fb0.v, acc[2][0], 0, 0, 0);
    acc[2][1] = __builtin_amdgcn_mfma_f32_16x16x32_bf16(fa.v, fb1.v, acc[2][1], 0, 0, 0);
    fa.q[0] = r30; fa.q[1] = r31;
    acc[3][0] = __builtin_amdgcn_mfma_f32_16x16x32_bf16(fa.v, fb0.v, acc[3][0], 0, 0, 0);
    acc[3][1] = __builtin_amdgcn_mfma_f32_16x16x32_bf16(fa.v, fb1.v, acc[3][1], 0, 0, 0);
    __syncthreads();
  }

  if (t < 4) {
    ushort_t* dst = (t < 2) ? lidQK : camQK;
    const int colbase = (t & 1) * 128 + w * 32 + lane15;
    #pragma unroll
    for (int q = 0; q < 4; ++q)
      #pragma unroll
      for (int tt = 0; tt < 2; ++tt)
        #pragma unroll
        for (int r = 0; r < 4; ++r) {
          int n = y * 64 + q * 16 + g * 4 + r;
          dst[(size_t)n * 256 + colbase + tt * 16] = f2bf(acc[q][tt][r]);
        }
  } else {
    ushort_t* dst = (t == 4) ? camV : lidV;
    ushort_t* pout = dst + (size_t)(w * 32 + lane15) * 4096 + y * 64 + g * 4;
    #pragma unroll
    for (int q = 0; q < 4; ++q) {
      ushort4 p0, p1;
      p0.x = f2bf(acc[q][0][0]); p0.y = f2bf(acc[q][0][1]);
      p0.z = f2bf(acc[q][0][2]); p0.w = f2bf(acc[q][0][3]);
      p1.x = f2bf(acc[q][1][0]); p1.y = f2bf(acc[q][1][1]);
      p1.z = f2bf(acc[q][1][2]); p1.w = f2bf(acc[q][1][3]);
      *(ushort4*)(pout + q * 16)             = p0;
      *(ushort4*)(pout + 16 * 4096 + q * 16) = p1;
    }
  }
}

// ---------------------------------------------------------------------------
// flash attention v5: 32x32 MFMA, in-register P (cvt_pk + permlane32_swap),
// lane-local softmax (one shfl_xor(32)/iter), no Ps LDS, defer-rescale.
// grid (32 qblk, 4 h, 4 = attn*2+half), block 256 = 4 waves x 32 q-rows.
// 2048 keys/block, KVBLK=64. Q pre-scaled by scale*log2e (exp2 domain).
// S^T = mfma32x32x16(K, Q): lane holds col q=l&31; rows k = crow(reg,hi).
// K LDS rows 80B (bank 4*(5r+c)%8, stripe-injective); V rows 144B (4*(r+c)%8).
// ---------------------------------------------------------------------------
__global__ __launch_bounds__(256) void flash_attn_mfma(
    const ushort_t* __restrict__ lidQK, const ushort_t* __restrict__ camQK,
    const ushort_t* __restrict__ camV, const ushort_t* __restrict__ lidV,
    ushort_t* __restrict__ OP, float2* __restrict__ ML) {
  const int i0    = blockIdx.x * 128;
  const int h     = blockIdx.y;
  const int attn  = blockIdx.z >> 1;
  const int half  = blockIdx.z & 1;
  const int kbase = half * 2048;
  const ushort_t* QK = attn ? camQK : lidQK;

  __shared__ __align__(16) ushort_t Ks[2][64 * 40];   // [k][32d], 80B rows
  __shared__ __align__(16) ushort_t Vt[2][64 * 72];   // [tensor*32+d][64k], 144B rows

  const int tid = threadIdx.x;
  const int w = tid >> 6, l = tid & 63;
  const int q31 = l & 31, hi = l >> 5;
  const int q0w = i0 + w * 32;

  // staging: thread -> (row 0..63, chunk 0..3); V covers chunks c and c+4
  const int srow = tid >> 2, sc = tid & 3;
  const ushort_t* Kg = QK + (size_t)(kbase + srow) * 256 + 128 + h * 32 + sc * 8;
  const ushort_t* Vg = ((srow >> 5) ? lidV : camV)
                     + (size_t)(h * 32 + (srow & 31)) * N_PIX + kbase;

  // Q B-frags (2 d-slices) direct from global: lane = col q, elems d=s*16+hi*8+j
  fragU qf0, qf1;
  qf0.u4 = *(const uint4*)(QK + (size_t)(q0w + q31) * 256 + h * 32 + hi * 8);
  qf1.u4 = *(const uint4*)(QK + (size_t)(q0w + q31) * 256 + h * 32 + 16 + hi * 8);

  { // prologue staging
    uint4 k4 = *(const uint4*)Kg;
    uint4 va = *(const uint4*)(Vg + sc * 8);
    uint4 vb = *(const uint4*)(Vg + (sc + 4) * 8);
    *(uint4*)(&Ks[0][srow * 40 + sc * 8]) = k4;
    *(uint4*)(&Vt[0][srow * 72 + sc * 8]) = va;
    *(uint4*)(&Vt[0][srow * 72 + (sc + 4) * 8]) = vb;
  }
  __syncthreads();

  f32x16 Oc = (f32x16)0.f, Ol = (f32x16)0.f;
  float lrun = 0.f, mrun = -1e30f;

  for (int it = 0; it < 32; ++it) {
    const int cur = it & 1, nxt = cur ^ 1;
    const bool more = (it + 1) < 32;
    uint4 kn, van, vbn;
    if (more) {
      kn  = *(const uint4*)(Kg + (size_t)(it + 1) * 16384);
      van = *(const uint4*)(Vg + (it + 1) * 64 + sc * 8);
      vbn = *(const uint4*)(Vg + (it + 1) * 64 + (sc + 4) * 8);
    }

    // ---- QK: S^T (2 k-tiles x 2 d-slices) ----
    const ushort_t* kb = &Ks[cur][0];
    fragU k00, k01, k10, k11;
    k00.u4 = *(const uint4*)(kb + q31 * 40 + hi * 8);
    k01.u4 = *(const uint4*)(kb + q31 * 40 + 16 + hi * 8);
    k10.u4 = *(const uint4*)(kb + (32 + q31) * 40 + hi * 8);
    k11.u4 = *(const uint4*)(kb + (32 + q31) * 40 + 16 + hi * 8);
    f32x16 S0, S1;
    __builtin_amdgcn_s_setprio(1);
    S0 = __builtin_amdgcn_mfma_f32_32x32x16_bf16(k00.v, qf0.v, (f32x16)0.f, 0, 0, 0);
    S0 = __builtin_amdgcn_mfma_f32_32x32x16_bf16(k01.v, qf1.v, S0, 0, 0, 0);
    S1 = __builtin_amdgcn_mfma_f32_32x32x16_bf16(k10.v, qf0.v, (f32x16)0.f, 0, 0, 0);
    S1 = __builtin_amdgcn_mfma_f32_32x32x16_bf16(k11.v, qf1.v, S1, 0, 0, 0);
    __builtin_amdgcn_s_setprio(0);

    // ---- softmax (lane-pair local; q = l&31) ----
    float mx = S0[0];
    #pragma unroll
    for (int j = 1; j < 16; ++j) mx = fmaxf(mx, S0[j]);
    #pragma unroll
    for (int j = 0; j < 16; ++j) mx = fmaxf(mx, S1[j]);
    if (__any(mx > mrun + 6.f)) {
      float gm = mx;
      gm = fmaxf(gm, __shfl_xor(gm, 1));
      gm = fmaxf(gm, __shfl_xor(gm, 2));
      gm = fmaxf(gm, __shfl_xor(gm, 4));
      gm = fmaxf(gm, __shfl_xor(gm, 8));
      gm = fmaxf(gm, __shfl_xor(gm, 16));
      gm = fmaxf(gm, __shfl_xor(gm, 32));
      if (gm > mrun) {
        float corr = __builtin_amdgcn_exp2f(mrun - gm);
        Oc = Oc * corr;
        Ol = Ol * corr;
        lrun *= corr;
        mrun = gm;
      }
    }
    float ps = 0.f;
    #pragma unroll
    for (int j = 0; j < 16; ++j) {
      float p = __builtin_amdgcn_exp2f(S0[j] - mrun);
      S0[j] = p; ps += p;
    }
    #pragma unroll
    for (int j = 0; j < 16; ++j) {
      float p = __builtin_amdgcn_exp2f(S1[j] - mrun);
      S1[j] = p; ps += p;
    }
    ps += __shfl_xor(ps, 32);
    lrun += ps;

    // ---- P -> A-frags: cvt_pk pairs + permlane32_swap (DST.row1 <-> SRC.row0)
    fragU pa0, pa1, pa2, pa3;
    {
      unsigned a0, a1, b0, b1;
      asm("v_cvt_pk_bf16_f32 %0, %1, %2" : "=v"(a0) : "v"(S0[0]),  "v"(S0[1]));
      asm("v_cvt_pk_bf16_f32 %0, %1, %2" : "=v"(a1) : "v"(S0[2]),  "v"(S0[3]));
      asm("v_cvt_pk_bf16_f32 %0, %1, %2" : "=v"(b0) : "v"(S0[4]),  "v"(S0[5]));
      asm("v_cvt_pk_bf16_f32 %0, %1, %2" : "=v"(b1) : "v"(S0[6]),  "v"(S0[7]));
      uint2v r0 = __builtin_amdgcn_permlane32_swap(a0, b0, false, false);
      uint2v r1 = __builtin_amdgcn_permlane32_swap(a1, b1, false, false);
      pa0.u[0] = r0[0]; pa0.u[1] = r1[0]; pa0.u[2] = r0[1]; pa0.u[3] = r1[1];
      asm("v_cvt_pk_bf16_f32 %0, %1, %2" : "=v"(a0) : "v"(S0[8]),  "v"(S0[9]));
      asm("v_cvt_pk_bf16_f32 %0, %1, %2" : "=v"(a1) : "v"(S0[10]), "v"(S0[11]));
      asm("v_cvt_pk_bf16_f32 %0, %1, %2" : "=v"(b0) : "v"(S0[12]), "v"(S0[13]));
      asm("v_cvt_pk_bf16_f32 %0, %1, %2" : "=v"(b1) : "v"(S0[14]), "v"(S0[15]));
      r0 = __builtin_amdgcn_permlane32_swap(a0, b0, false, false);
      r1 = __builtin_amdgcn_permlane32_swap(a1, b1, false, false);
      pa1.u[0] = r0[0]; pa1.u[1] = r1[0]; pa1.u[2] = r0[1]; pa1.u[3] = r1[1];
      asm("v_cvt_pk_bf16_f32 %0, %1, %2" : "=v"(a0) : "v"(S1[0]),  "v"(S1[1]));
      asm("v_cvt_pk_bf16_f32 %0, %1, %2" : "=v"(a1) : "v"(S1[2]),  "v"(S1[3]));
      asm("v_cvt_pk_bf16_f32 %0, %1, %2" : "=v"(b0) : "v"(S1[4]),  "v"(S1[5]));
      asm("v_cvt_pk_bf16_f32 %0, %1, %2" : "=v"(b1) : "v"(S1[6]),  "v"(S1[7]));
      r0 = __builtin_amdgcn_permlane32_swap(a0, b0, false, false);
      r1 = __builtin_amdgcn_permlane32_swap(a1, b1, false, false);
      pa2.u[0] = r0[0]; pa2.u[1] = r1[0]; pa2.u[2] = r0[1]; pa2.u[3] = r1[1];
      asm("v_cvt_pk_bf16_f32 %0, %1, %2" : "=v"(a0) : "v"(S1[8]),  "v"(S1[9]));
      asm("v_cvt_pk_bf16_f32 %0, %1, %2" : "=v"(a1) : "v"(S1[10]), "v"(S1[11]));
      asm("v_cvt_pk_bf16_f32 %0, %1, %2" : "=v"(b0) : "v"(S1[12]), "v"(S1[13]));
      asm("v_cvt_pk_bf16_f32 %0, %1, %2" : "=v"(b1) : "v"(S1[14]), "v"(S1[15]));
      r0 = __builtin_amdgcn_permlane32_swap(a0, b0, false, false);
      r1 = __builtin_amdgcn_permlane32_swap(a1, b1, false, false);
      pa3.u[0] = r0[0]; pa3.u[1] = r1[0]; pa3.u[2] = r0[1]; pa3.u[3] = r1[1];
    }

    // ---- PV: 4 k-slices x 2 tensors ----
    const ushort_t* vb = &Vt[cur][0];
    __builtin_amdgcn_s_setprio(1);
    {
      fragU vc, vl;
      vc.u4 = *(const uint4*)(vb + q31 * 72 + hi * 8);
      vl.u4 = *(const uint4*)(vb + (32 + q31) * 72 + hi * 8);
      Oc = __builtin_amdgcn_mfma_f32_32x32x16_bf16(pa0.v, vc.v, Oc, 0, 0, 0);
      Ol = __builtin_amdgcn_mfma_f32_32x32x16_bf16(pa0.v, vl.v, Ol, 0, 0, 0);
      vc.u4 = *(const uint4*)(vb + q31 * 72 + 16 + hi * 8);
      vl.u4 = *(const uint4*)(vb + (32 + q31) * 72 + 16 + hi * 8);
      Oc = __builtin_amdgcn_mfma_f32_32x32x16_bf16(pa1.v, vc.v, Oc, 0, 0, 0);
      Ol = __builtin_amdgcn_mfma_f32_32x32x16_bf16(pa1.v, vl.v, Ol, 0, 0, 0);
      vc.u4 = *(const uint4*)(vb + q31 * 72 + 32 + hi * 8);
      vl.u4 = *(const uint4*)(vb + (32 + q31) * 72 + 32 + hi * 8);
      Oc = __builtin_amdgcn_mfma_f32_32x32x16_bf16(pa2.v, vc.v, Oc, 0, 0, 0);
      Ol = __builtin_amdgcn_mfma_f32_32x32x16_bf16(pa2.v, vl.v, Ol, 0, 0, 0);
      vc.u4 = *(const uint4*)(vb + q31 * 72 + 48 + hi * 8);
      vl.u4 = *(const uint4*)(vb + (32 + q31) * 72 + 48 + hi * 8);
      Oc = __builtin_amdgcn_mfma_f32_32x32x16_bf16(pa3.v, vc.v, Oc, 0, 0, 0);
      Ol = __builtin_amdgcn_mfma_f32_32x32x16_bf16(pa3.v, vl.v, Ol, 0, 0, 0);
    }
    __builtin_amdgcn_s_setprio(0);

    if (more) {
      *(uint4*)(&Ks[nxt][srow * 40 + sc * 8]) = kn;
      *(uint4*)(&Vt[nxt][srow * 72 + sc * 8]) = van;
      *(uint4*)(&Vt[nxt][srow * 72 + (sc + 4) * 8]) = vbn;
    }
    __syncthreads();
  }

  // epilogue: unnormalized bf16 partials; rows q = crow(reg,hi)
  ushort_t* OPc = OP + (size_t)((attn * 2 + half) * 2 + 0) * 4096 * 128;
  ushort_t* OPl = OP + (size_t)((attn * 2 + half) * 2 + 1) * 4096 * 128;
  const int d = h * 32 + q31;
  #pragma unroll
  for (int reg = 0; reg < 16; ++reg) {
    int n = q0w + (reg & 3) + 8 * (reg >> 2) + 4 * hi;
    OPc[(size_t)n * 128 + d] = f2bf(Oc[reg]);
    OPl[(size_t)n * 128 + d] = f2bf(Ol[reg]);
  }
  if (l < 32) {
    float2 v; v.x = mrun; v.y = lrun;
    ML[(size_t)(attn * 2 + half) * 4096 + q0w + l] = v;
  }
}

// ---------------------------------------------------------------------------
// proj_mfma: key-split combine + projection GEMM + residual + bias
// -> padded bf16 fuser-conv inputs. grid (64 nblk, 4 ot), block 256.
// ---------------------------------------------------------------------------
__global__ __launch_bounds__(256) void proj_mfma_k(
    const ushort_t* __restrict__ OP, const float2* __restrict__ ML,
    const ushort_t* __restrict__ Wlid, const ushort_t* __restrict__ Wcam,
    const float* __restrict__ cam_enc, const float* __restrict__ lidar_bev,
    const float* __restrict__ cam_proj_b, const float* __restrict__ lid_proj_b,
    ushort_t* __restrict__ fm, ushort_t* __restrict__ fh) {
  const int n0 = blockIdx.x * 64;
  const int ot = blockIdx.y;
  const int attn = (ot == 0 || ot == 2) ? 1 : 0;
  const int vt = ot >> 1;
  const int tid = threadIdx.x;
  const int w = tid >> 6, l = tid & 63;
  const int m = l & 15, g = l >> 4;

  const ushort_t* Oa = OP + (size_t)((attn * 2 + 0) * 2 + vt) * 4096 * 128;
  const ushort_t* Ob = OP + (size_t)((attn * 2 + 1) * 2 + vt) * 4096 * 128;
  const float2* MLa = ML + (size_t)(attn * 2 + 0) * 4096;
  const float2* MLb = ML + (size_t)(attn * 2 + 1) * 4096;

  const int arow = n0 + w * 16 + m;
  float2 mla = MLa[arow], mlb = MLb[arow];
  float M  = fmaxf(mla.x, mlb.x);
  float wa = __builtin_amdgcn_exp2f(mla.x - M);
  float wb = __builtin_amdgcn_exp2f(mlb.x - M);
  float dn = wa * mla.y + wb * mlb.y;
  float aa = wa / dn, ab = wb / dn;

  fragU afr[4];
  #pragma unroll
  for (int s = 0; s < 4; ++s) {
    fragU xa, xb;
    xa.u4 = *(const uint4*)(Oa + (size_t)arow * 128 + s * 32 + g * 8);
    xb.u4 = *(const uint4*)(Ob + (size_t)arow * 128 + s * 32 + g * 8);
    #pragma unroll
    for (int j = 0; j < 8; ++j)
      afr[s].us[j] = f2bf(aa * bf2f(xa.us[j]) + ab * bf2f(xb.us[j]));
  }

  const ushort_t* W = (ot == 1) ? Wcam : Wlid;
  f32x4 acc[8];
  #pragma unroll
  for (int t = 0; t < 8; ++t) acc[t] = (f32x4){0.f, 0.f, 0.f, 0.f};
  #pragma unroll
  for (int s = 0; s < 4; ++s) {
    #pragma unroll
    for (int t = 0; t < 8; ++t) {
      fragU bfr;
      bfr.u4 = *(const uint4*)(W + (size_t)(t * 16 + m) * 128 + s * 32 + g * 8);
      acc[t] = __builtin_amdgcn_mfma_f32_16x16x32_bf16(afr[s].v, bfr.v, acc[t], 0, 0, 0);
    }
  }

  const float* res  = (ot < 2) ? cam_enc : lidar_bev;
  const float* bias = (ot == 1) ? cam_proj_b : lid_proj_b;
  const int doff = ot * 126;
  #pragma unroll
  for (int t = 0; t < 8; ++t) {
    int co = t * 16 + m;
    if (co < 126) {
      float b = bias[co];
      #pragma unroll
      for (int r = 0; r < 4; ++r) {
        int n = n0 + w * 16 + g * 4 + r;
        float v = acc[t][r] + res[(size_t)co * N_PIX + n] + b;
        unsigned short bf = f2bf(v);
        int y = n >> 6, x = n & 63;
        fm[(doff + co) * 4224 + (y + 1) * 64 + x]      = bf;
        fh[(doff + co) * 4356 + (y + 1) * 66 + x + 1]  = bf;
      }
    }
  }
}

// ---------------------------------------------------------------------------
extern "C" void kernel_launch(void* const* d_in, const int* in_sizes, int n_in,
                              void* d_out, int out_size, void* d_ws, size_t ws_size,
                              hipStream_t stream) {
  (void)in_sizes; (void)n_in; (void)out_size; (void)ws_size;
  const float* lidar_bev  = (const float*)d_in[0];
  const float* cam_bev    = (const float*)d_in[1];
  const float* cam_enc_w  = (const float*)d_in[2];
  const float* cam_enc_b  = (const float*)d_in[3];
  const float* cam_v_w    = (const float*)d_in[4];
  const float* cam_qk_w   = (const float*)d_in[5];
  const float* cam_proj_w = (const float*)d_in[6];
  const float* cam_proj_b = (const float*)d_in[7];
  const float* lid_v_w    = (const float*)d_in[8];
  const float* lid_qk_w   = (const float*)d_in[9];
  const float* lid_proj_w = (const float*)d_in[10];
  const float* lid_proj_b = (const float*)d_in[11];
  const float* fuser_w    = (const float*)d_in[12];
  float* out = (float*)d_out;

  char* p = (char*)d_ws;
  ushort_t* arena = (ushort_t*)p;                  // 9 x [128][4096] bf16 (conv)
  ushort_t* OP    = (ushort_t*)p;                  // [2a][2half][2v][4096][128] bf16, aliased
  float2*   ML    = (float2*)(p + 8388608);        // [2a][2half][4096] float2
  ushort_t* lidQK = (ushort_t*)(p + 9437184);      // [4096][256] bf16
  ushort_t* camQK = (ushort_t*)(p + 11534336);
  ushort_t* camV  = (ushort_t*)(p + 13631488);     // [128][4096] bf16
  ushort_t* lidV  = (ushort_t*)(p + 14680064);
  float*    cam_enc = (float*)(p + 15728640);      // [126][4096] f32
  ushort_t* Wp_c    = (ushort_t*)(p + 17793024);   // [9][128][96]
  ushort_t* Wp_f    = (ushort_t*)(p + 18014208);   // [9][128][512]
  ushort_t* Wp_lid  = (ushort_t*)(p + 19193856);   // [128][128]
  ushort_t* Wp_cam  = (ushort_t*)(p + 19226624);   // [128][128]
  ushort_t* Wq      = (ushort_t*)(p + 19259392);   // [6][128][128]
  ushort_t* lidBF   = (ushort_t*)(p + 19456000);   // [128][4096] (126 used)
  ushort_t* camBF   = (ushort_t*)(p + 20504576);   // [128][4096] (126 used)
  ushort_t* camBF_m = (ushort_t*)(p + 21553152);   // [96][66][64]
  ushort_t* camBF_h = (ushort_t*)(p + 22364160);   // [96][66][66]
  ushort_t* fusBF_m = (ushort_t*)(p + 23200512);   // [512][66][64]
  ushort_t* fusBF_h = (ushort_t*)(p + 27525888);   // [512][66][66] (end 31986432)

  zero_span_k<<<2548, 256, 0, stream>>>((uint4*)(p + 21553152), 652080);
  pack_w_k<<<3248, 256, 0, stream>>>(cam_enc_w, fuser_w, lid_proj_w, cam_proj_w,
                                     lid_qk_w, cam_qk_w, cam_v_w, lid_v_w,
                                     Wp_c, Wp_f, Wp_lid, Wp_cam, Wq);
  convert_in_k<<<3296, 256, 0, stream>>>(cam_bev, lidar_bev, camBF_m, camBF_h, lidBF);

  conv_mfma_k<<<dim3(64, 9), 256, 0, stream>>>(camBF_m, camBF_h, Wp_c, arena, 96, 3);
  reduce9_k<<<dim3(2, 126), 256, 0, stream>>>(arena, cam_enc, camBF, cam_enc_b);

  qkv_mfma_k<<<dim3(64, 6), 256, 0, stream>>>(lidBF, camBF, Wq, lidQK, camQK, camV, lidV);
  flash_attn_mfma<<<dim3(32, 4, 4), 256, 0, stream>>>(lidQK, camQK, camV, lidV, OP, ML);
  proj_mfma_k<<<dim3(64, 4), 256, 0, stream>>>(OP, ML, Wp_lid, Wp_cam, cam_enc, lidar_bev,
                                               cam_proj_b, lid_proj_b, fusBF_m, fusBF_h);

  conv_mfma_k<<<dim3(64, 9), 256, 0, stream>>>(fusBF_m, fusBF_h, Wp_f, arena, 512, 16);
  reduce9_k<<<dim3(2, 126), 256, 0, stream>>>(arena, out, nullptr, nullptr);
}